// Round 4
// baseline (630.461 us; speedup 1.0000x reference)
//
#include <hip/hip_runtime.h>
#include <math.h>

#define NN 50000
#define NE 800000
#define GG 50

typedef unsigned int u32;
typedef unsigned short u16;
typedef float v2f __attribute__((ext_vector_type(2)));
typedef short bf16x8 __attribute__((ext_vector_type(8)));
typedef float f32x4 __attribute__((ext_vector_type(4)));

__device__ __forceinline__ float uaf(u32 x) { return __uint_as_float(x); }

__device__ __forceinline__ u32 bfpack2(float x, float y) {
    u32 a = __float_as_uint(x), b = __float_as_uint(y);
    a = (a + 0x7fffu + ((a >> 16) & 1u)) >> 16;
    b = (b + 0x7fffu + ((b >> 16) & 1u)) & 0xffff0000u;
    return b | a;
}
__device__ __forceinline__ u16 bf16of(float x) {
    u32 a = __float_as_uint(x);
    return (u16)((a + 0x7fffu + ((a >> 16) & 1u)) >> 16);
}

// packed fp32 math (v_pk_fma_f32 / v_pk_max_f32 on gfx950)
__device__ __forceinline__ v2f fma2(v2f a, v2f b, v2f c) { return __builtin_elementwise_fma(a, b, c); }
__device__ __forceinline__ v2f max2(v2f a, v2f b) { return __builtin_elementwise_max(a, b); }

// DPP partial reductions (VALU pipe). ctrl must be an immediate.
template <int CTRL>
__device__ __forceinline__ float dpp_add(float v) {
    int t = __builtin_amdgcn_update_dpp(0, __float_as_int(v), CTRL, 0xf, 0xf, true);
    return v + __int_as_float(t);
}
__device__ __forceinline__ float swz_xor16_add(float v) {
    int t = __builtin_amdgcn_ds_swizzle(__float_as_int(v), 0x401F);
    return v + __int_as_float(t);
}
// after RED4+xor16: each 32-group holds its sum; total = group0 + group1 (uniform)
__device__ __forceinline__ float total64(float v) {
    return __int_as_float(__builtin_amdgcn_readlane(__float_as_int(v), 0))
         + __int_as_float(__builtin_amdgcn_readlane(__float_as_int(v), 32));
}
#define RED4_STAGES(q)  do {                                                    \
    _Pragma("unroll") for (int j = 0; j < 4; ++j) q[j] = dpp_add<0xB1>(q[j]);  \
    _Pragma("unroll") for (int j = 0; j < 4; ++j) q[j] = dpp_add<0x4E>(q[j]);  \
    _Pragma("unroll") for (int j = 0; j < 4; ++j) q[j] = dpp_add<0x141>(q[j]); \
    _Pragma("unroll") for (int j = 0; j < 4; ++j) q[j] = dpp_add<0x140>(q[j]); \
} while (0)

// ---------------- utility ----------------
__global__ void zero_u32_kernel(u32* __restrict__ p, int n) {
    int i = blockIdx.x * 256 + threadIdx.x;
    if (i < n) p[i] = 0u;
}

// ---------------- mega prep: count_edges + wpack(WT1) + wpack(WT2) ----------------
__global__ __launch_bounds__(256) void mega_prep_kernel(
    const int* __restrict__ ei, u32* __restrict__ counts,
    const float* __restrict__ w1a, const float* __restrict__ w1b, const float* __restrict__ w1c,
    u32* __restrict__ WT1,
    const float* __restrict__ w2a, const float* __restrict__ w2b, const float* __restrict__ w2c,
    u32* __restrict__ WT2)
{
    int b = blockIdx.x;
    int t = threadIdx.x;
    if (b < 3125) {
        int e = b * 256 + t;
        if (e < NE) atomicAdd(&counts[ei[NE + e]], 1u);
    } else if (b < 3125 + 96) {
        int i = (b - 3125) * 256 + t;           // 0 .. 3*128*64-1
        const int per = 128 * 64;
        int mat = i / per;
        int r = i - mat * per;
        const float* W = (mat == 0) ? w1a : (mat == 1) ? w1b : w1c;
        int col = r >> 6, c = r & 63;
        WT1[i] = bfpack2(W[(size_t)(2 * c) * 128 + col], W[(size_t)(2 * c + 1) * 128 + col]);
    } else {
        int i = (b - 3221) * 256 + t;           // 0 .. 3*64*64-1
        const int per = 64 * 64;
        int mat = i / per;
        int r = i - mat * per;
        const float* W = (mat == 0) ? w2a : (mat == 1) ? w2b : w2c;
        int col = r >> 6, c = r & 63;
        WT2[i] = bfpack2(W[(size_t)(2 * c) * 64 + col], W[(size_t)(2 * c + 1) * 64 + col]);
    }
}

// ---------------- scan part1 (blocks 0-48) + GEMM1 (blocks 49+) ----------------
// gemm1: reads x fp32 directly, packs to bf16 while staging, stages X once,
// loops over the 6 column tiles of WT1.
__global__ __launch_bounds__(256) void scan1_gemm1_kernel(
    const u32* __restrict__ counts, u32* __restrict__ bsums,
    const float* __restrict__ X, const u32* __restrict__ Wt,
    u16* __restrict__ out0, float* __restrict__ out1, float* __restrict__ out2,
    const float* __restrict__ b0, const float* __restrict__ b1, const float* __restrict__ b2,
    int n)
{
    __shared__ __align__(16) u32 SMEM[64 * 68 * 2];
    int t = threadIdx.x;
    if (blockIdx.x < 49) {
        u32* ls = SMEM;
        int base = blockIdx.x * 1024 + t * 4;
        u32 s = 0;
#pragma unroll
        for (int j = 0; j < 4; ++j) { int idx = base + j; if (idx < NN) s += counts[idx]; }
        ls[t] = s;
        __syncthreads();
        for (int off = 128; off > 0; off >>= 1) {
            if (t < off) ls[t] += ls[t + off];
            __syncthreads();
        }
        if (t == 0) bsums[blockIdx.x] = ls[0];
        return;
    }
    u32* Xs = SMEM;
    u32* Ws = SMEM + 64 * 68;
    int row0 = (blockIdx.x - 49) * 64;
#pragma unroll
    for (int i = 0; i < 16; ++i) {
        int flat = t + 256 * i;
        int r = flat >> 6, c = flat & 63;
        int gr = row0 + r;
        u32 v = 0u;
        if (gr < n) {
            float2 f = *(const float2*)(X + (size_t)gr * 128 + c * 2);
            v = bfpack2(f.x, f.y);
        }
        Xs[r * 68 + c] = v;
    }
    int w = t >> 6, lane = t & 63;
    int l15 = lane & 15, quad = lane >> 4;
    for (int nb = 0; nb < 6; ++nb) {
#pragma unroll
        for (int i = 0; i < 16; ++i) {
            int flat = t + 256 * i;
            int cc = flat >> 6, c = flat & 63;
            Ws[cc * 68 + c] = Wt[(size_t)(nb * 64 + cc) * 64 + c];
        }
        __syncthreads();
        f32x4 acc[4] = {};
#pragma unroll
        for (int kk = 0; kk < 4; ++kk) {
            bf16x8 af = *(const bf16x8*)&Xs[(w * 16 + l15) * 68 + kk * 16 + quad * 4];
#pragma unroll
            for (int j = 0; j < 4; ++j) {
                bf16x8 bf = *(const bf16x8*)&Ws[(j * 16 + l15) * 68 + kk * 16 + quad * 4];
                acc[j] = __builtin_amdgcn_mfma_f32_16x16x32_bf16(af, bf, acc[j], 0, 0, 0);
            }
        }
        int mat = nb >> 1;
        int col0 = (nb & 1) * 64;
        const float* bp = (mat == 0) ? b0 : (mat == 1) ? b1 : b2;
#pragma unroll
        for (int j = 0; j < 4; ++j) {
            int col = col0 + j * 16 + l15;
            float bb = bp[col];
#pragma unroll
            for (int r = 0; r < 4; ++r) {
                int grow = row0 + w * 16 + quad * 4 + r;
                if (grow < n) {
                    float v = acc[j][r] + bb;
                    if (mat == 0) out0[(size_t)grow * 128 + col] = bf16of(v);
                    else if (mat == 1) out1[(size_t)grow * 128 + col] = v;
                    else out2[(size_t)grow * 128 + col] = v;
                }
            }
        }
        __syncthreads();
    }
}

// ---------------- scan final (block-sum scan inlined as a wave scan) ----------------
__global__ __launch_bounds__(256) void scan_final_kernel(
    const u32* __restrict__ counts, const u32* __restrict__ bsums, int* __restrict__ rowptr)
{
    __shared__ u32 ls[256];
    __shared__ u32 prefsh;
    int t = threadIdx.x;
    if (t < 64) {
        u32 v = (t < 49) ? bsums[t] : 0u;
#pragma unroll
        for (int off = 1; off < 64; off <<= 1) {
            u32 tv = __shfl_up(v, off, 64);
            if (t >= off) v += tv;
        }
        u32 ex = __shfl_up(v, 1, 64);
        if (t == 0) ex = 0u;
        if (t == (int)blockIdx.x) prefsh = ex;
    }
    __syncthreads();
    u32 bpref = prefsh;
    int base = blockIdx.x * 1024 + t * 4;
    u32 c[4];
    u32 s = 0;
#pragma unroll
    for (int j = 0; j < 4; ++j) { int idx = base + j; c[j] = (idx < NN) ? counts[idx] : 0u; s += c[j]; }
    ls[t] = s;
    __syncthreads();
    for (int off = 1; off < 256; off <<= 1) {
        u32 add = (t >= off) ? ls[t - off] : 0u;
        __syncthreads();
        ls[t] += add;
        __syncthreads();
    }
    u32 run = ls[t] - s + bpref;
#pragma unroll
    for (int j = 0; j < 4; ++j) { int idx = base + j; if (idx < NN) { rowptr[idx] = (int)run; } run += c[j]; }
    if (blockIdx.x == 0 && t == 0) rowptr[NN] = NE;
}

// ---------------- scatter: CSR-order srcs + CSR-order packed edge attrs ----------------
// Packs ea fp32->bf16 directly into CSR order (kills the pack_ea pass and makes the
// gat kernels' edge-attr reads sequential AND wave-uniform -> s_load eligible).
__global__ __launch_bounds__(256) void scatter_pack_kernel(
    const int* __restrict__ ei, const float* __restrict__ ea, const int* __restrict__ rowptr,
    u32* __restrict__ cursors, int* __restrict__ srcs, u32* __restrict__ eahs)
{
    int e = blockIdx.x * 256 + threadIdx.x;
    if (e < NE) {
        int sn = ei[e];
        int d = ei[NE + e];
        u32 pos = atomicAdd(&cursors[d], 1u);
        int slot = rowptr[d] + (int)pos;
        srcs[slot] = sn;
        const float4* s4 = (const float4*)(ea + (size_t)e * 16);
        float4 f0 = s4[0], f1 = s4[1], f2 = s4[2], f3 = s4[3];
        uint4 o0 = {bfpack2(f0.x, f0.y), bfpack2(f0.z, f0.w), bfpack2(f1.x, f1.y), bfpack2(f1.z, f1.w)};
        uint4 o1 = {bfpack2(f2.x, f2.y), bfpack2(f2.z, f2.w), bfpack2(f3.x, f3.y), bfpack2(f3.z, f3.w)};
        *(uint4*)(eahs + (size_t)slot * 8) = o0;
        *(uint4*)(eahs + (size_t)slot * 8 + 4) = o1;
    }
}

// ---------------- fused GATv2 layer 1 (H=2, C=64) ----------------
// CSR-ordered uniform edge stream: srcs/eahs loads are wave-uniform & sequential
// (scalar pipe); bf16 unpack on SALU; e-dot via packed v_pk_fma_f32.
__global__ __launch_bounds__(256) void gat1_fused_kernel(
    const u32* __restrict__ xlp, const float* __restrict__ xr,
    const u32* __restrict__ eahs, const int* __restrict__ srcs,
    const int* __restrict__ rowptr, const float* __restrict__ We,
    const float* __restrict__ att, const float* __restrict__ bias,
    float* __restrict__ out)
{
    int lane = threadIdx.x & 63;
    int d = (blockIdx.x * 256 + threadIdx.x) >> 6;
    if (d >= NN) return;
    int du = __builtin_amdgcn_readfirstlane(d);
    int beg = rowptr[du], end = rowptr[du + 1];
    int c0 = lane * 2;
    v2f w[16];
#pragma unroll
    for (int k = 0; k < 16; ++k) {
        float2 t2 = *(const float2*)(We + k * 128 + c0);
        w[k] = (v2f){t2.x, t2.y};
    }
    float a0 = att[c0], a1 = att[c0 + 1];
    float2 bt = *(const float2*)(bias + c0);
    float2 xq = *(const float2*)(xr + (size_t)du * 128 + c0);
    v2f xrv = {xq.x, xq.y};

    float s = 0.f;
    v2f acc = {0.f, 0.f};

    int i = beg;
    for (; i + 4 <= end; i += 4) {
        float q[4]; v2f xv[4];
#pragma unroll
        for (int j = 0; j < 4; ++j) {
            const u32* er = eahs + (size_t)(i + j) * 8;   // uniform -> s_load
            int sn = srcs[i + j];                         // uniform -> sgpr
            u32 px = xlp[(size_t)sn * 64 + lane];
            v2f e = {0.f, 0.f};
#pragma unroll
            for (int kk = 0; kk < 8; ++kk) {
                u32 pk = er[kk];
                float s1 = uaf(pk << 16), s2 = uaf(pk & 0xffff0000u);  // SALU
                e = fma2(w[2 * kk],     (v2f){s1, s1}, e);
                e = fma2(w[2 * kk + 1], (v2f){s2, s2}, e);
            }
            xv[j] = (v2f){uaf(px << 16), uaf(px & 0xffff0000u)};
            v2f mm = xv[j] + xrv + e;
            v2f lk = max2(mm, mm * 0.2f);
            q[j] = fmaf(lk.x, a0, lk.y * a1);
        }
        RED4_STAGES(q);
#pragma unroll
        for (int j = 0; j < 4; ++j) q[j] = swz_xor16_add(q[j]);
        float w0 = __expf(q[0]), w1 = __expf(q[1]);
        float w2 = __expf(q[2]), w3 = __expf(q[3]);
        s += (w0 + w1) + (w2 + w3);
        acc = fma2(xv[0], (v2f){w0, w0}, acc);
        acc = fma2(xv[1], (v2f){w1, w1}, acc);
        acc = fma2(xv[2], (v2f){w2, w2}, acc);
        acc = fma2(xv[3], (v2f){w3, w3}, acc);
    }
    for (; i < end; ++i) {
        const u32* er = eahs + (size_t)i * 8;
        int sn = srcs[i];
        u32 px = xlp[(size_t)sn * 64 + lane];
        v2f e = {0.f, 0.f};
#pragma unroll
        for (int kk = 0; kk < 8; ++kk) {
            u32 pk = er[kk];
            float s1 = uaf(pk << 16), s2 = uaf(pk & 0xffff0000u);
            e = fma2(w[2 * kk],     (v2f){s1, s1}, e);
            e = fma2(w[2 * kk + 1], (v2f){s2, s2}, e);
        }
        v2f xv = {uaf(px << 16), uaf(px & 0xffff0000u)};
        v2f mm = xv + xrv + e;
        v2f lk = max2(mm, mm * 0.2f);
        float p = fmaf(lk.x, a0, lk.y * a1);
        p = dpp_add<0xB1>(p);
        p = dpp_add<0x4E>(p);
        p = dpp_add<0x141>(p);
        p = dpp_add<0x140>(p);
        p = swz_xor16_add(p);
        float ww = __expf(p);
        s += ww;
        acc = fma2(xv, (v2f){ww, ww}, acc);
    }
    float inv = 1.f / (s + 1e-16f);
    float2 o;
    o.x = fmaf(acc.x, inv, bt.x);
    o.y = fmaf(acc.y, inv, bt.y);
    *(float2*)(out + (size_t)d * 128 + c0) = o;
}

// ---------------- fused GATv2 layer 2 (H=1, C=64) ----------------
__global__ __launch_bounds__(256) void gat2_fused_kernel(
    const u16* __restrict__ xlp, const float* __restrict__ xr,
    const u32* __restrict__ eahs, const int* __restrict__ srcs,
    const int* __restrict__ rowptr, const float* __restrict__ We,
    const float* __restrict__ att, const float* __restrict__ bias,
    float* __restrict__ out)
{
    int lane = threadIdx.x & 63;
    int d = (blockIdx.x * 256 + threadIdx.x) >> 6;
    if (d >= NN) return;
    int du = __builtin_amdgcn_readfirstlane(d);
    int beg = rowptr[du], end = rowptr[du + 1];
    float w[16];
#pragma unroll
    for (int k = 0; k < 16; ++k) w[k] = We[k * 64 + lane];
    float a0 = att[lane];
    float bb = bias[lane];
    float xrv = xr[(size_t)du * 64 + lane];

    float s = 0.f, acc = 0.f;

    int i = beg;
    for (; i + 4 <= end; i += 4) {
        float q[4]; float xv[4];
#pragma unroll
        for (int j = 0; j < 4; ++j) {
            const u32* er = eahs + (size_t)(i + j) * 8;   // uniform -> s_load
            int sn = srcs[i + j];                         // uniform -> sgpr
            xv[j] = uaf((u32)xlp[(size_t)sn * 64 + lane] << 16);
            float e = 0.f;
#pragma unroll
            for (int kk = 0; kk < 8; ++kk) {
                u32 pk = er[kk];
                float s1 = uaf(pk << 16), s2 = uaf(pk & 0xffff0000u);  // SALU
                e = fmaf(s1, w[2 * kk], e);
                e = fmaf(s2, w[2 * kk + 1], e);
            }
            float mm = xv[j] + xrv + e;
            mm = fmaxf(mm, 0.2f * mm);
            q[j] = mm * a0;
        }
        RED4_STAGES(q);
#pragma unroll
        for (int j = 0; j < 4; ++j) { q[j] = swz_xor16_add(q[j]); q[j] = total64(q[j]); }
        float w0 = __expf(q[0]), w1 = __expf(q[1]);
        float w2 = __expf(q[2]), w3 = __expf(q[3]);
        s += (w0 + w1) + (w2 + w3);
        acc += fmaf(w0, xv[0], fmaf(w1, xv[1], fmaf(w2, xv[2], w3 * xv[3])));
    }
    for (; i < end; ++i) {
        const u32* er = eahs + (size_t)i * 8;
        int sn = srcs[i];
        float xv = uaf((u32)xlp[(size_t)sn * 64 + lane] << 16);
        float e = 0.f;
#pragma unroll
        for (int kk = 0; kk < 8; ++kk) {
            u32 pk = er[kk];
            float s1 = uaf(pk << 16), s2 = uaf(pk & 0xffff0000u);
            e = fmaf(s1, w[2 * kk], e);
            e = fmaf(s2, w[2 * kk + 1], e);
        }
        float mm = xv + xrv + e;
        mm = fmaxf(mm, 0.2f * mm);
        float p = mm * a0;
        p = dpp_add<0xB1>(p);
        p = dpp_add<0x4E>(p);
        p = dpp_add<0x141>(p);
        p = dpp_add<0x140>(p);
        p = swz_xor16_add(p);
        p = total64(p);
        float ww = __expf(p);
        s += ww;
        acc = fmaf(ww, xv, acc);
    }
    out[(size_t)d * 64 + lane] = acc / (s + 1e-16f) + bb;
}

// ---------------- fused MFMA GEMM, layer 2 (BN1+skip+ELU+pack in staging) ----------------
__global__ __launch_bounds__(256) void gemm2_fused_kernel(
    const float* __restrict__ H, const float* __restrict__ XPin,
    const float* __restrict__ stats, const float* __restrict__ bg, const float* __restrict__ bbv,
    const u32* __restrict__ Wt,
    u16* __restrict__ out0, float* __restrict__ out1, float* __restrict__ out2,
    const float* __restrict__ b0, const float* __restrict__ b1, const float* __restrict__ b2,
    int n)
{
    __shared__ __align__(16) u32 Xs[64 * 68];
    __shared__ __align__(16) u32 Ws[64 * 68];
    int t = threadIdx.x;
    int row0 = blockIdx.x * 64;
    int c = t & 63;
    int ch0 = 2 * c, ch1 = ch0 + 1;
    float mu0 = stats[ch0] * (1.f / NN), mu1 = stats[ch1] * (1.f / NN);
    float var0 = stats[128 + ch0] * (1.f / NN) - mu0 * mu0;
    float var1 = stats[128 + ch1] * (1.f / NN) - mu1 * mu1;
    float s0 = rsqrtf(var0 + 1e-5f) * bg[ch0];
    float s1 = rsqrtf(var1 + 1e-5f) * bg[ch1];
    float t0 = bbv[ch0] - mu0 * s0;
    float t1 = bbv[ch1] - mu1 * s1;
#pragma unroll
    for (int i = 0; i < 16; ++i) {
        int flat = t + 256 * i;
        int r = flat >> 6;
        int gr = row0 + r;
        u32 v = 0u;
        if (gr < n) {
            float2 hv = *(const float2*)(H + (size_t)gr * 128 + ch0);
            float2 xv = *(const float2*)(XPin + (size_t)gr * 128 + ch0);
            float v0 = fmaf(hv.x, s0, t0) + xv.x;
            float v1 = fmaf(hv.y, s1, t1) + xv.y;
            v0 = (v0 > 0.f) ? v0 : expm1f(v0);
            v1 = (v1 > 0.f) ? v1 : expm1f(v1);
            v = bfpack2(v0, v1);
        }
        Xs[r * 68 + c] = v;
    }
    int w = t >> 6, lane = t & 63;
    int l15 = lane & 15, quad = lane >> 4;
    for (int nb = 0; nb < 3; ++nb) {
#pragma unroll
        for (int i = 0; i < 16; ++i) {
            int flat = t + 256 * i;
            int cc = flat >> 6, cw = flat & 63;
            Ws[cc * 68 + cw] = Wt[(size_t)(nb * 64 + cc) * 64 + cw];
        }
        __syncthreads();
        f32x4 acc[4] = {};
#pragma unroll
        for (int kk = 0; kk < 4; ++kk) {
            bf16x8 af = *(const bf16x8*)&Xs[(w * 16 + l15) * 68 + kk * 16 + quad * 4];
#pragma unroll
            for (int j = 0; j < 4; ++j) {
                bf16x8 bf = *(const bf16x8*)&Ws[(j * 16 + l15) * 68 + kk * 16 + quad * 4];
                acc[j] = __builtin_amdgcn_mfma_f32_16x16x32_bf16(af, bf, acc[j], 0, 0, 0);
            }
        }
        const float* bp = (nb == 0) ? b0 : (nb == 1) ? b1 : b2;
#pragma unroll
        for (int j = 0; j < 4; ++j) {
            int col = j * 16 + l15;
            float bb = bp[col];
#pragma unroll
            for (int r = 0; r < 4; ++r) {
                int grow = row0 + w * 16 + quad * 4 + r;
                if (grow < n) {
                    float v = acc[j][r] + bb;
                    if (nb == 0) out0[(size_t)grow * 64 + col] = bf16of(v);
                    else if (nb == 1) out1[(size_t)grow * 64 + col] = v;
                    else out2[(size_t)grow * 64 + col] = v;
                }
            }
        }
        __syncthreads();
    }
}

// ---------------- batch-norm stats ----------------
template <int C>
__global__ __launch_bounds__(256) void bn_stats_kernel(const float* __restrict__ h, float* __restrict__ stats) {
    const int SUB = 256 / C;
    int t = threadIdx.x;
    int c = t & (C - 1);
    int rs = t / C;
    int r0 = blockIdx.x * 512;
    int r1 = min(NN, r0 + 512);
    float s = 0.f, s2 = 0.f;
    for (int r = r0 + rs; r < r1; r += SUB) {
        float v = h[(size_t)r * C + c];
        s += v; s2 = fmaf(v, v, s2);
    }
    __shared__ float ls[256], ls2[256];
    ls[t] = s; ls2[t] = s2;
    __syncthreads();
    if (rs == 0) {
        for (int j = 1; j < SUB; ++j) { s += ls[j * C + c]; s2 += ls2[j * C + c]; }
        atomicAdd(&stats[c], s);
        atomicAdd(&stats[C + c], s2);
    }
}

// ---------------- pool (BN2-apply + skip + ELU fused) + classifier ----------------
__global__ __launch_bounds__(256) void pool_cls_kernel(
    const float* __restrict__ D, const float* __restrict__ xp2,
    const float* __restrict__ stats, const float* __restrict__ bg, const float* __restrict__ bbv,
    const int* __restrict__ batch,
    const float* __restrict__ cw, const float* __restrict__ cb,
    float* __restrict__ outp)
{
    int g = blockIdx.x;
    int t = threadIdx.x;
    int lane = t & 63, w4 = t >> 6;
    float mu = stats[lane] * (1.f / NN);
    float var = stats[64 + lane] * (1.f / NN) - mu * mu;
    float sc = rsqrtf(var + 1e-5f) * bg[lane];
    float tb = bbv[lane] - mu * sc;
    int lo = 0, hi = NN;
    while (lo < hi) { int mid = (lo + hi) >> 1; if (batch[mid] < g) lo = mid + 1; else hi = mid; }
    int s0 = lo;
    hi = NN;
    while (lo < hi) { int mid = (lo + hi) >> 1; if (batch[mid] < g + 1) lo = mid + 1; else hi = mid; }
    int e0 = lo;
    float sum = 0.f, mx = -INFINITY;
    for (int r = s0 + w4; r < e0; r += 4) {
        float v = fmaf(D[(size_t)r * 64 + lane], sc, tb) + xp2[(size_t)r * 64 + lane];
        v = (v > 0.f) ? v : expm1f(v);
        sum += v; mx = fmaxf(mx, v);
    }
    __shared__ float lsum[256], lmax[256];
    lsum[t] = sum; lmax[t] = mx;
    __syncthreads();
    if (w4 == 0) {
        for (int j = 1; j < 4; ++j) { sum += lsum[j * 64 + lane]; mx = fmaxf(mx, lmax[j * 64 + lane]); }
        float cnt = (float)(e0 - s0);
        float mean = sum / fmaxf(cnt, 1.f);
#pragma unroll
        for (int c = 0; c < 2; ++c) {
            float v = fmaf(mean, cw[lane * 2 + c], mx * cw[(64 + lane) * 2 + c]);
            v = dpp_add<0xB1>(v);
            v = dpp_add<0x4E>(v);
            v = dpp_add<0x141>(v);
            v = dpp_add<0x140>(v);
            v = swz_xor16_add(v);
            v = total64(v);
            if (lane == 0) outp[g * 2 + c] = v + cb[c];
        }
    }
}

extern "C" void kernel_launch(void* const* d_in, const int* in_sizes, int n_in,
                              void* d_out, int out_size, void* d_ws, size_t ws_size,
                              hipStream_t stream)
{
    const float* x       = (const float*)d_in[0];
    const int*   ei      = (const int*)d_in[1];
    const float* ea      = (const float*)d_in[2];
    const int*   batch   = (const int*)d_in[3];
    const float* skip1_w = (const float*)d_in[4];
    const float* skip1_b = (const float*)d_in[5];
    const float* c1_wl   = (const float*)d_in[6];
    const float* c1_bl   = (const float*)d_in[7];
    const float* c1_wr   = (const float*)d_in[8];
    const float* c1_br   = (const float*)d_in[9];
    const float* c1_we   = (const float*)d_in[10];
    const float* c1_att  = (const float*)d_in[11];
    const float* c1_bias = (const float*)d_in[12];
    const float* bn1_g   = (const float*)d_in[13];
    const float* bn1_b   = (const float*)d_in[14];
    const float* skip2_w = (const float*)d_in[15];
    const float* skip2_b = (const float*)d_in[16];
    const float* c2_wl   = (const float*)d_in[17];
    const float* c2_bl   = (const float*)d_in[18];
    const float* c2_wr   = (const float*)d_in[19];
    const float* c2_br   = (const float*)d_in[20];
    const float* c2_we   = (const float*)d_in[21];
    const float* c2_att  = (const float*)d_in[22];
    const float* c2_bias = (const float*)d_in[23];
    const float* bn2_g   = (const float*)d_in[24];
    const float* bn2_b   = (const float*)d_in[25];
    const float* cls_w   = (const float*)d_in[26];
    const float* cls_b   = (const float*)d_in[27];
    float* outp = (float*)d_out;

    float* ws = (float*)d_ws;
    size_t o = 0;
    float* A   = ws + o; o += 6400000;   // XL1P bf16 [n][128]; layer2: XL2P bf16 (lower) + xr2 fp32 (upper)
    float* B   = ws + o; o += 6400000;   // xr1 fp32 [n][128]
    float* Cb  = ws + o; o += 6400000;   // xp1 fp32 [n][128]
    float* D   = ws + o; o += 6400000;   // h1 pre-BN [n][128] ; later h2 pre-BN [n][64]
    int*   SRCS  = (int*)(ws + o); o += 800000;    // CSR-ordered src nodes
    u32*   EAHS  = (u32*)(ws + o); o += 6400000;   // CSR-ordered ea packed bf16 [E][8]
    u32*   XPx   = (u32*)(ws + o); o += 3200000;   // xp2 fp32 [n][64]
    u32*   WT1   = (u32*)(ws + o); o += 24576;     // [384][64]
    u32*   WT2   = (u32*)(ws + o); o += 12288;     // [192][64]
    u32*   COUNTS  = (u32*)(ws + o); o += 50000;
    u32*   CURSORS = (u32*)(ws + o); o += 50000;
    float* STATS1  = ws + o; o += 256;
    float* STATS2  = ws + o; o += 128;
    int*   ROWPTR  = (int*)(ws + o); o += 50016;
    u32*   BSUMS   = (u32*)(ws + o); o += 64;

    u16*   XL1P = (u16*)A;               // [n][128] bf16
    u16*   XL2P = (u16*)A;               // [n][64] bf16 (layer 2)
    float* xr2  = A + 3200000;
    float* xp2  = (float*)XPx;           // [n][64] fp32

    // zero COUNTS + CURSORS + STATS1 + STATS2 (contiguous, 100384 u32)
    zero_u32_kernel<<<(100384 + 255) / 256, 256, 0, stream>>>(COUNTS, 100384);
    // count_edges + wpack(WT1) + wpack(WT2) in one launch
    mega_prep_kernel<<<3269, 256, 0, stream>>>(ei, COUNTS,
        c1_wl, c1_wr, skip1_w, WT1, c2_wl, c2_wr, skip2_w, WT2);
    // scan part1 (49 blocks) runs concurrently with GEMM1 (782 blocks)
    scan1_gemm1_kernel<<<831, 256, 0, stream>>>(COUNTS, BSUMS, x, WT1,
        XL1P, B, Cb, c1_bl, c1_br, skip1_b, NN);
    scan_final_kernel<<<49, 256, 0, stream>>>(COUNTS, BSUMS, ROWPTR);
    scatter_pack_kernel<<<3125, 256, 0, stream>>>(ei, ea, ROWPTR, CURSORS, SRCS, EAHS);

    // ---- layer 1 ----
    gat1_fused_kernel<<<NN / 4, 256, 0, stream>>>((const u32*)XL1P, B, EAHS, SRCS, ROWPTR,
        c1_we, c1_att, c1_bias, D);
    bn_stats_kernel<128><<<98, 256, 0, stream>>>(D, STATS1);

    // ---- layer 2 (BN1-apply + skip + ELU fused into the GEMM staging) ----
    gemm2_fused_kernel<<<782, 256, 0, stream>>>(D, Cb, STATS1, bn1_g, bn1_b, WT2,
        XL2P, xr2, xp2, c2_bl, c2_br, skip2_b, NN);
    gat2_fused_kernel<<<NN / 4, 256, 0, stream>>>(XL2P, xr2, EAHS, SRCS, ROWPTR,
        c2_we, c2_att, c2_bias, D);
    bn_stats_kernel<64><<<98, 256, 0, stream>>>(D, STATS2);

    // ---- pool + BN2-apply + classifier fused ----
    pool_cls_kernel<<<GG, 256, 0, stream>>>(D, xp2, STATS2, bn2_g, bn2_b, batch, cls_w, cls_b, outp);
}

// Round 7
// 552.676 us; speedup vs baseline: 1.1407x; 1.1407x over previous
//
#include <hip/hip_runtime.h>
#include <math.h>

#define NN 50000
#define NE 800000
#define GG 50

typedef unsigned int u32;
typedef unsigned short u16;
typedef float v2f __attribute__((ext_vector_type(2)));
typedef short bf16x8 __attribute__((ext_vector_type(8)));
typedef float f32x4 __attribute__((ext_vector_type(4)));

__device__ __forceinline__ float uaf(u32 x) { return __uint_as_float(x); }

__device__ __forceinline__ u32 bfpack2(float x, float y) {
    u32 a = __float_as_uint(x), b = __float_as_uint(y);
    a = (a + 0x7fffu + ((a >> 16) & 1u)) >> 16;
    b = (b + 0x7fffu + ((b >> 16) & 1u)) & 0xffff0000u;
    return b | a;
}
__device__ __forceinline__ u16 bf16of(float x) {
    u32 a = __float_as_uint(x);
    return (u16)((a + 0x7fffu + ((a >> 16) & 1u)) >> 16);
}

// monotonic float<->u32 encoding for atomicMax on floats
__device__ __forceinline__ u32 fenc(float x) {
    u32 u = __float_as_uint(x);
    return (u >> 31) ? ~u : (u | 0x80000000u);
}
__device__ __forceinline__ float fdec(u32 m) {
    return (m >> 31) ? uaf(m & 0x7fffffffu) : uaf(~m);
}

// packed fp32 math (v_pk_fma_f32 / v_pk_max_f32 on gfx950)
__device__ __forceinline__ v2f fma2(v2f a, v2f b, v2f c) { return __builtin_elementwise_fma(a, b, c); }
__device__ __forceinline__ v2f max2(v2f a, v2f b) { return __builtin_elementwise_max(a, b); }

// DPP partial reductions (VALU pipe). ctrl must be an immediate.
template <int CTRL>
__device__ __forceinline__ float dpp_add(float v) {
    int t = __builtin_amdgcn_update_dpp(0, __float_as_int(v), CTRL, 0xf, 0xf, true);
    return v + __int_as_float(t);
}
__device__ __forceinline__ float swz_xor16_add(float v) {
    int t = __builtin_amdgcn_ds_swizzle(__float_as_int(v), 0x401F);
    return v + __int_as_float(t);
}
// after RED4+xor16: each 32-group holds its sum; total = group0 + group1 (uniform)
__device__ __forceinline__ float total64(float v) {
    return __int_as_float(__builtin_amdgcn_readlane(__float_as_int(v), 0))
         + __int_as_float(__builtin_amdgcn_readlane(__float_as_int(v), 32));
}
#define RED4_STAGES(q)  do {                                                    \
    _Pragma("unroll") for (int j = 0; j < 4; ++j) q[j] = dpp_add<0xB1>(q[j]);  \
    _Pragma("unroll") for (int j = 0; j < 4; ++j) q[j] = dpp_add<0x4E>(q[j]);  \
    _Pragma("unroll") for (int j = 0; j < 4; ++j) q[j] = dpp_add<0x141>(q[j]); \
    _Pragma("unroll") for (int j = 0; j < 4; ++j) q[j] = dpp_add<0x140>(q[j]); \
} while (0)

// ---------------- utility ----------------
__global__ void zero_u32_kernel(u32* __restrict__ p, int n) {
    int i = blockIdx.x * 256 + threadIdx.x;
    if (i < n) p[i] = 0u;
}

// ---------------- mega prep: count_edges + wpack(WT1) + wpack(WT2) ----------------
__global__ __launch_bounds__(256) void mega_prep_kernel(
    const int* __restrict__ ei, u32* __restrict__ counts,
    const float* __restrict__ w1a, const float* __restrict__ w1b, const float* __restrict__ w1c,
    u32* __restrict__ WT1,
    const float* __restrict__ w2a, const float* __restrict__ w2b, const float* __restrict__ w2c,
    u32* __restrict__ WT2)
{
    int b = blockIdx.x;
    int t = threadIdx.x;
    if (b < 3125) {
        int e = b * 256 + t;
        if (e < NE) atomicAdd(&counts[ei[NE + e]], 1u);
    } else if (b < 3125 + 96) {
        int i = (b - 3125) * 256 + t;           // 0 .. 3*128*64-1
        const int per = 128 * 64;
        int mat = i / per;
        int r = i - mat * per;
        const float* W = (mat == 0) ? w1a : (mat == 1) ? w1b : w1c;
        int col = r >> 6, c = r & 63;
        WT1[i] = bfpack2(W[(size_t)(2 * c) * 128 + col], W[(size_t)(2 * c + 1) * 128 + col]);
    } else {
        int i = (b - 3221) * 256 + t;           // 0 .. 3*64*64-1
        const int per = 64 * 64;
        int mat = i / per;
        int r = i - mat * per;
        const float* W = (mat == 0) ? w2a : (mat == 1) ? w2b : w2c;
        int col = r >> 6, c = r & 63;
        WT2[i] = bfpack2(W[(size_t)(2 * c) * 64 + col], W[(size_t)(2 * c + 1) * 64 + col]);
    }
}

// ---------------- scan part1 (blocks 0-48) + GEMM1 (blocks 49+) ----------------
__global__ __launch_bounds__(256) void scan1_gemm1_kernel(
    const u32* __restrict__ counts, u32* __restrict__ bsums,
    const float* __restrict__ X, const u32* __restrict__ Wt,
    u16* __restrict__ out0, float* __restrict__ out1, float* __restrict__ out2,
    const float* __restrict__ b0, const float* __restrict__ b1, const float* __restrict__ b2,
    int n)
{
    __shared__ __align__(16) u32 SMEM[64 * 68 * 2];
    int t = threadIdx.x;
    if (blockIdx.x < 49) {
        u32* ls = SMEM;
        int base = blockIdx.x * 1024 + t * 4;
        u32 s = 0;
#pragma unroll
        for (int j = 0; j < 4; ++j) { int idx = base + j; if (idx < NN) s += counts[idx]; }
        ls[t] = s;
        __syncthreads();
        for (int off = 128; off > 0; off >>= 1) {
            if (t < off) ls[t] += ls[t + off];
            __syncthreads();
        }
        if (t == 0) bsums[blockIdx.x] = ls[0];
        return;
    }
    u32* Xs = SMEM;
    u32* Ws = SMEM + 64 * 68;
    int row0 = (blockIdx.x - 49) * 64;
#pragma unroll
    for (int i = 0; i < 16; ++i) {
        int flat = t + 256 * i;
        int r = flat >> 6, c = flat & 63;
        int gr = row0 + r;
        u32 v = 0u;
        if (gr < n) {
            float2 f = *(const float2*)(X + (size_t)gr * 128 + c * 2);
            v = bfpack2(f.x, f.y);
        }
        Xs[r * 68 + c] = v;
    }
    int w = t >> 6, lane = t & 63;
    int l15 = lane & 15, quad = lane >> 4;
    for (int nb = 0; nb < 6; ++nb) {
#pragma unroll
        for (int i = 0; i < 16; ++i) {
            int flat = t + 256 * i;
            int cc = flat >> 6, c = flat & 63;
            Ws[cc * 68 + c] = Wt[(size_t)(nb * 64 + cc) * 64 + c];
        }
        __syncthreads();
        f32x4 acc[4] = {};
#pragma unroll
        for (int kk = 0; kk < 4; ++kk) {
            bf16x8 af = *(const bf16x8*)&Xs[(w * 16 + l15) * 68 + kk * 16 + quad * 4];
#pragma unroll
            for (int j = 0; j < 4; ++j) {
                bf16x8 bf = *(const bf16x8*)&Ws[(j * 16 + l15) * 68 + kk * 16 + quad * 4];
                acc[j] = __builtin_amdgcn_mfma_f32_16x16x32_bf16(af, bf, acc[j], 0, 0, 0);
            }
        }
        int mat = nb >> 1;
        int col0 = (nb & 1) * 64;
        const float* bp = (mat == 0) ? b0 : (mat == 1) ? b1 : b2;
#pragma unroll
        for (int j = 0; j < 4; ++j) {
            int col = col0 + j * 16 + l15;
            float bb = bp[col];
#pragma unroll
            for (int r = 0; r < 4; ++r) {
                int grow = row0 + w * 16 + quad * 4 + r;
                if (grow < n) {
                    float v = acc[j][r] + bb;
                    if (mat == 0) out0[(size_t)grow * 128 + col] = bf16of(v);
                    else if (mat == 1) out1[(size_t)grow * 128 + col] = v;
                    else out2[(size_t)grow * 128 + col] = v;
                }
            }
        }
        __syncthreads();
    }
}

// ---------------- scan final (block-sum scan inlined as a wave scan) ----------------
__global__ __launch_bounds__(256) void scan_final_kernel(
    const u32* __restrict__ counts, const u32* __restrict__ bsums, int* __restrict__ rowptr)
{
    __shared__ u32 ls[256];
    __shared__ u32 prefsh;
    int t = threadIdx.x;
    if (t < 64) {
        u32 v = (t < 49) ? bsums[t] : 0u;
#pragma unroll
        for (int off = 1; off < 64; off <<= 1) {
            u32 tv = __shfl_up(v, off, 64);
            if (t >= off) v += tv;
        }
        u32 ex = __shfl_up(v, 1, 64);
        if (t == 0) ex = 0u;
        if (t == (int)blockIdx.x) prefsh = ex;
    }
    __syncthreads();
    u32 bpref = prefsh;
    int base = blockIdx.x * 1024 + t * 4;
    u32 c[4];
    u32 s = 0;
#pragma unroll
    for (int j = 0; j < 4; ++j) { int idx = base + j; c[j] = (idx < NN) ? counts[idx] : 0u; s += c[j]; }
    ls[t] = s;
    __syncthreads();
    for (int off = 1; off < 256; off <<= 1) {
        u32 add = (t >= off) ? ls[t - off] : 0u;
        __syncthreads();
        ls[t] += add;
        __syncthreads();
    }
    u32 run = ls[t] - s + bpref;
#pragma unroll
    for (int j = 0; j < 4; ++j) { int idx = base + j; if (idx < NN) { rowptr[idx] = (int)run; } run += c[j]; }
    if (blockIdx.x == 0 && t == 0) rowptr[NN] = NE;
}

// ---------------- scatter: CSR-order srcs + CSR-order packed edge attrs ----------------
__global__ __launch_bounds__(256) void scatter_pack_kernel(
    const int* __restrict__ ei, const float* __restrict__ ea, const int* __restrict__ rowptr,
    u32* __restrict__ cursors, int* __restrict__ srcs, u32* __restrict__ eahs)
{
    int e = blockIdx.x * 256 + threadIdx.x;
    if (e < NE) {
        int sn = ei[e];
        int d = ei[NE + e];
        u32 pos = atomicAdd(&cursors[d], 1u);
        int slot = rowptr[d] + (int)pos;
        srcs[slot] = sn;
        const float4* s4 = (const float4*)(ea + (size_t)e * 16);
        float4 f0 = s4[0], f1 = s4[1], f2 = s4[2], f3 = s4[3];
        uint4 o0 = {bfpack2(f0.x, f0.y), bfpack2(f0.z, f0.w), bfpack2(f1.x, f1.y), bfpack2(f1.z, f1.w)};
        uint4 o1 = {bfpack2(f2.x, f2.y), bfpack2(f2.z, f2.w), bfpack2(f3.x, f3.y), bfpack2(f3.z, f3.w)};
        *(uint4*)(eahs + (size_t)slot * 8) = o0;
        *(uint4*)(eahs + (size_t)slot * 8 + 4) = o1;
    }
}

// ---------------- fused GATv2 layer 1 (H=2, C=64) ----------------
__global__ __launch_bounds__(256) void gat1_fused_kernel(
    const u32* __restrict__ xlp, const float* __restrict__ xr,
    const u32* __restrict__ eahs, const int* __restrict__ srcs,
    const int* __restrict__ rowptr, const float* __restrict__ We,
    const float* __restrict__ att, const float* __restrict__ bias,
    float* __restrict__ out)
{
    int lane = threadIdx.x & 63;
    int d = (blockIdx.x * 256 + threadIdx.x) >> 6;
    if (d >= NN) return;
    int du = __builtin_amdgcn_readfirstlane(d);
    int beg = rowptr[du], end = rowptr[du + 1];
    int c0 = lane * 2;
    v2f w[16];
#pragma unroll
    for (int k = 0; k < 16; ++k) {
        float2 t2 = *(const float2*)(We + k * 128 + c0);
        w[k] = (v2f){t2.x, t2.y};
    }
    float a0 = att[c0], a1 = att[c0 + 1];
    float2 bt = *(const float2*)(bias + c0);
    float2 xq = *(const float2*)(xr + (size_t)du * 128 + c0);
    v2f xrv = {xq.x, xq.y};

    float s = 0.f;
    v2f acc = {0.f, 0.f};

    int i = beg;
    for (; i + 4 <= end; i += 4) {
        float q[4]; v2f xv[4];
#pragma unroll
        for (int j = 0; j < 4; ++j) {
            const u32* er = eahs + (size_t)(i + j) * 8;   // uniform -> s_load
            int sn = srcs[i + j];                         // uniform -> sgpr
            u32 px = xlp[(size_t)sn * 64 + lane];
            v2f e = {0.f, 0.f};
#pragma unroll
            for (int kk = 0; kk < 8; ++kk) {
                u32 pk = er[kk];
                float s1 = uaf(pk << 16), s2 = uaf(pk & 0xffff0000u);  // SALU
                e = fma2(w[2 * kk],     (v2f){s1, s1}, e);
                e = fma2(w[2 * kk + 1], (v2f){s2, s2}, e);
            }
            xv[j] = (v2f){uaf(px << 16), uaf(px & 0xffff0000u)};
            v2f mm = xv[j] + xrv + e;
            v2f lk = max2(mm, mm * 0.2f);
            q[j] = fmaf(lk.x, a0, lk.y * a1);
        }
        RED4_STAGES(q);
#pragma unroll
        for (int j = 0; j < 4; ++j) q[j] = swz_xor16_add(q[j]);
        float w0 = __expf(q[0]), w1 = __expf(q[1]);
        float w2 = __expf(q[2]), w3 = __expf(q[3]);
        s += (w0 + w1) + (w2 + w3);
        acc = fma2(xv[0], (v2f){w0, w0}, acc);
        acc = fma2(xv[1], (v2f){w1, w1}, acc);
        acc = fma2(xv[2], (v2f){w2, w2}, acc);
        acc = fma2(xv[3], (v2f){w3, w3}, acc);
    }
    for (; i < end; ++i) {
        const u32* er = eahs + (size_t)i * 8;
        int sn = srcs[i];
        u32 px = xlp[(size_t)sn * 64 + lane];
        v2f e = {0.f, 0.f};
#pragma unroll
        for (int kk = 0; kk < 8; ++kk) {
            u32 pk = er[kk];
            float s1 = uaf(pk << 16), s2 = uaf(pk & 0xffff0000u);
            e = fma2(w[2 * kk],     (v2f){s1, s1}, e);
            e = fma2(w[2 * kk + 1], (v2f){s2, s2}, e);
        }
        v2f xv = {uaf(px << 16), uaf(px & 0xffff0000u)};
        v2f mm = xv + xrv + e;
        v2f lk = max2(mm, mm * 0.2f);
        float p = fmaf(lk.x, a0, lk.y * a1);
        p = dpp_add<0xB1>(p);
        p = dpp_add<0x4E>(p);
        p = dpp_add<0x141>(p);
        p = dpp_add<0x140>(p);
        p = swz_xor16_add(p);
        float ww = __expf(p);
        s += ww;
        acc = fma2(xv, (v2f){ww, ww}, acc);
    }
    float inv = 1.f / (s + 1e-16f);
    float2 o;
    o.x = fmaf(acc.x, inv, bt.x);
    o.y = fmaf(acc.y, inv, bt.y);
    *(float2*)(out + (size_t)d * 128 + c0) = o;
}

// ---------------- fused GATv2 layer 2 (H=1, C=64) ----------------
__global__ __launch_bounds__(256) void gat2_fused_kernel(
    const u16* __restrict__ xlp, const float* __restrict__ xr,
    const u32* __restrict__ eahs, const int* __restrict__ srcs,
    const int* __restrict__ rowptr, const float* __restrict__ We,
    const float* __restrict__ att, const float* __restrict__ bias,
    float* __restrict__ out)
{
    int lane = threadIdx.x & 63;
    int d = (blockIdx.x * 256 + threadIdx.x) >> 6;
    if (d >= NN) return;
    int du = __builtin_amdgcn_readfirstlane(d);
    int beg = rowptr[du], end = rowptr[du + 1];
    float w[16];
#pragma unroll
    for (int k = 0; k < 16; ++k) w[k] = We[k * 64 + lane];
    float a0 = att[lane];
    float bb = bias[lane];
    float xrv = xr[(size_t)du * 64 + lane];

    float s = 0.f, acc = 0.f;

    int i = beg;
    for (; i + 4 <= end; i += 4) {
        float q[4]; float xv[4];
#pragma unroll
        for (int j = 0; j < 4; ++j) {
            const u32* er = eahs + (size_t)(i + j) * 8;   // uniform -> s_load
            int sn = srcs[i + j];                         // uniform -> sgpr
            xv[j] = uaf((u32)xlp[(size_t)sn * 64 + lane] << 16);
            float e = 0.f;
#pragma unroll
            for (int kk = 0; kk < 8; ++kk) {
                u32 pk = er[kk];
                float s1 = uaf(pk << 16), s2 = uaf(pk & 0xffff0000u);  // SALU
                e = fmaf(s1, w[2 * kk], e);
                e = fmaf(s2, w[2 * kk + 1], e);
            }
            float mm = xv[j] + xrv + e;
            mm = fmaxf(mm, 0.2f * mm);
            q[j] = mm * a0;
        }
        RED4_STAGES(q);
#pragma unroll
        for (int j = 0; j < 4; ++j) { q[j] = swz_xor16_add(q[j]); q[j] = total64(q[j]); }
        float w0 = __expf(q[0]), w1 = __expf(q[1]);
        float w2 = __expf(q[2]), w3 = __expf(q[3]);
        s += (w0 + w1) + (w2 + w3);
        acc += fmaf(w0, xv[0], fmaf(w1, xv[1], fmaf(w2, xv[2], w3 * xv[3])));
    }
    for (; i < end; ++i) {
        const u32* er = eahs + (size_t)i * 8;
        int sn = srcs[i];
        float xv = uaf((u32)xlp[(size_t)sn * 64 + lane] << 16);
        float e = 0.f;
#pragma unroll
        for (int kk = 0; kk < 8; ++kk) {
            u32 pk = er[kk];
            float s1 = uaf(pk << 16), s2 = uaf(pk & 0xffff0000u);
            e = fmaf(s1, w[2 * kk], e);
            e = fmaf(s2, w[2 * kk + 1], e);
        }
        float mm = xv + xrv + e;
        mm = fmaxf(mm, 0.2f * mm);
        float p = mm * a0;
        p = dpp_add<0xB1>(p);
        p = dpp_add<0x4E>(p);
        p = dpp_add<0x141>(p);
        p = dpp_add<0x140>(p);
        p = swz_xor16_add(p);
        p = total64(p);
        float ww = __expf(p);
        s += ww;
        acc = fmaf(ww, xv, acc);
    }
    out[(size_t)d * 64 + lane] = acc / (s + 1e-16f) + bb;
}

// ---------------- fused MFMA GEMM, layer 2 (BN1+skip+ELU+pack in staging) ----------------
__global__ __launch_bounds__(256) void gemm2_fused_kernel(
    const float* __restrict__ H, const float* __restrict__ XPin,
    const float* __restrict__ stats, const float* __restrict__ bg, const float* __restrict__ bbv,
    const u32* __restrict__ Wt,
    u16* __restrict__ out0, float* __restrict__ out1, float* __restrict__ out2,
    const float* __restrict__ b0, const float* __restrict__ b1, const float* __restrict__ b2,
    int n)
{
    __shared__ __align__(16) u32 Xs[64 * 68];
    __shared__ __align__(16) u32 Ws[64 * 68];
    int t = threadIdx.x;
    int row0 = blockIdx.x * 64;
    int c = t & 63;
    int ch0 = 2 * c, ch1 = ch0 + 1;
    float mu0 = stats[ch0] * (1.f / NN), mu1 = stats[ch1] * (1.f / NN);
    float var0 = stats[128 + ch0] * (1.f / NN) - mu0 * mu0;
    float var1 = stats[128 + ch1] * (1.f / NN) - mu1 * mu1;
    float s0 = rsqrtf(var0 + 1e-5f) * bg[ch0];
    float s1 = rsqrtf(var1 + 1e-5f) * bg[ch1];
    float t0 = bbv[ch0] - mu0 * s0;
    float t1 = bbv[ch1] - mu1 * s1;
#pragma unroll
    for (int i = 0; i < 16; ++i) {
        int flat = t + 256 * i;
        int r = flat >> 6;
        int gr = row0 + r;
        u32 v = 0u;
        if (gr < n) {
            float2 hv = *(const float2*)(H + (size_t)gr * 128 + ch0);
            float2 xv = *(const float2*)(XPin + (size_t)gr * 128 + ch0);
            float v0 = fmaf(hv.x, s0, t0) + xv.x;
            float v1 = fmaf(hv.y, s1, t1) + xv.y;
            v0 = (v0 > 0.f) ? v0 : expm1f(v0);
            v1 = (v1 > 0.f) ? v1 : expm1f(v1);
            v = bfpack2(v0, v1);
        }
        Xs[r * 68 + c] = v;
    }
    int w = t >> 6, lane = t & 63;
    int l15 = lane & 15, quad = lane >> 4;
    for (int nb = 0; nb < 3; ++nb) {
#pragma unroll
        for (int i = 0; i < 16; ++i) {
            int flat = t + 256 * i;
            int cc = flat >> 6, cw = flat & 63;
            Ws[cc * 68 + cw] = Wt[(size_t)(nb * 64 + cc) * 64 + cw];
        }
        __syncthreads();
        f32x4 acc[4] = {};
#pragma unroll
        for (int kk = 0; kk < 4; ++kk) {
            bf16x8 af = *(const bf16x8*)&Xs[(w * 16 + l15) * 68 + kk * 16 + quad * 4];
#pragma unroll
            for (int j = 0; j < 4; ++j) {
                bf16x8 bf = *(const bf16x8*)&Ws[(j * 16 + l15) * 68 + kk * 16 + quad * 4];
                acc[j] = __builtin_amdgcn_mfma_f32_16x16x32_bf16(af, bf, acc[j], 0, 0, 0);
            }
        }
        const float* bp = (nb == 0) ? b0 : (nb == 1) ? b1 : b2;
#pragma unroll
        for (int j = 0; j < 4; ++j) {
            int col = j * 16 + l15;
            float bb = bp[col];
#pragma unroll
            for (int r = 0; r < 4; ++r) {
                int grow = row0 + w * 16 + quad * 4 + r;
                if (grow < n) {
                    float v = acc[j][r] + bb;
                    if (nb == 0) out0[(size_t)grow * 64 + col] = bf16of(v);
                    else if (nb == 1) out1[(size_t)grow * 64 + col] = v;
                    else out2[(size_t)grow * 64 + col] = v;
                }
            }
        }
        __syncthreads();
    }
}

// ---------------- batch-norm stats ----------------
template <int C>
__global__ __launch_bounds__(256) void bn_stats_kernel(const float* __restrict__ h, float* __restrict__ stats) {
    const int SUB = 256 / C;
    int t = threadIdx.x;
    int c = t & (C - 1);
    int rs = t / C;
    int r0 = blockIdx.x * 512;
    int r1 = min(NN, r0 + 512);
    float s = 0.f, s2 = 0.f;
    for (int r = r0 + rs; r < r1; r += SUB) {
        float v = h[(size_t)r * C + c];
        s += v; s2 = fmaf(v, v, s2);
    }
    __shared__ float ls[256], ls2[256];
    ls[t] = s; ls2[t] = s2;
    __syncthreads();
    if (rs == 0) {
        for (int j = 1; j < SUB; ++j) { s += ls[j * C + c]; s2 += ls2[j * C + c]; }
        atomicAdd(&stats[c], s);
        atomicAdd(&stats[C + c], s2);
    }
}

// ---------------- pool accumulate: BN2+skip+ELU fused, per-graph atomic sum/max ----------------
// batch is sorted, so each wave accumulates locally and flushes atomics only at
// graph boundaries. 391 blocks x 128 rows -> full CU occupancy (fixes 50-block
// pool_cls at 2% occupancy / 109us).
__global__ __launch_bounds__(256) void pool_acc_kernel(
    const float* __restrict__ D, const float* __restrict__ xp2,
    const float* __restrict__ stats, const float* __restrict__ bg, const float* __restrict__ bbv,
    const int* __restrict__ batch,
    float* __restrict__ psum, u32* __restrict__ pmax)
{
    int t = threadIdx.x;
    int lane = t & 63, rs = t >> 6;
    float mu = stats[lane] * (1.f / NN);
    float var = stats[64 + lane] * (1.f / NN) - mu * mu;
    float sc = rsqrtf(var + 1e-5f) * bg[lane];
    float tb = bbv[lane] - mu * sc;
    int r0 = blockIdx.x * 128;
    int r1 = min(NN, r0 + 128);
    int curg = -1;
    float sum = 0.f, mx = -INFINITY;
    for (int r = r0 + rs; r < r1; r += 4) {
        int g = batch[r];               // wave-uniform (lane indexes channel only)
        if (g != curg) {
            if (curg >= 0) {
                atomicAdd(&psum[curg * 64 + lane], sum);
                atomicMax(&pmax[curg * 64 + lane], fenc(mx));
            }
            curg = g; sum = 0.f; mx = -INFINITY;
        }
        float v = fmaf(D[(size_t)r * 64 + lane], sc, tb) + xp2[(size_t)r * 64 + lane];
        v = (v > 0.f) ? v : expm1f(v);
        sum += v; mx = fmaxf(mx, v);
    }
    if (curg >= 0) {
        atomicAdd(&psum[curg * 64 + lane], sum);
        atomicMax(&pmax[curg * 64 + lane], fenc(mx));
    }
}

// ---------------- pool finalize + classifier (tiny) ----------------
__global__ __launch_bounds__(64) void pool_fin_kernel(
    const float* __restrict__ psum, const u32* __restrict__ pmax,
    const int* __restrict__ batch,
    const float* __restrict__ cw, const float* __restrict__ cb,
    float* __restrict__ outp)
{
    int g = blockIdx.x;
    int lane = threadIdx.x;
    int lo = 0, hi = NN;
    while (lo < hi) { int mid = (lo + hi) >> 1; if (batch[mid] < g) lo = mid + 1; else hi = mid; }
    int s0 = lo;
    hi = NN;
    while (lo < hi) { int mid = (lo + hi) >> 1; if (batch[mid] < g + 1) lo = mid + 1; else hi = mid; }
    int e0 = lo;
    float cnt = (float)(e0 - s0);
    float mean = psum[g * 64 + lane] / fmaxf(cnt, 1.f);
    float mx = fdec(pmax[g * 64 + lane]);
#pragma unroll
    for (int c = 0; c < 2; ++c) {
        float v = fmaf(mean, cw[lane * 2 + c], mx * cw[(64 + lane) * 2 + c]);
        v = dpp_add<0xB1>(v);
        v = dpp_add<0x4E>(v);
        v = dpp_add<0x141>(v);
        v = dpp_add<0x140>(v);
        v = swz_xor16_add(v);
        v = total64(v);
        if (lane == 0) outp[g * 2 + c] = v + cb[c];
    }
}

extern "C" void kernel_launch(void* const* d_in, const int* in_sizes, int n_in,
                              void* d_out, int out_size, void* d_ws, size_t ws_size,
                              hipStream_t stream)
{
    const float* x       = (const float*)d_in[0];
    const int*   ei      = (const int*)d_in[1];
    const float* ea      = (const float*)d_in[2];
    const int*   batch   = (const int*)d_in[3];
    const float* skip1_w = (const float*)d_in[4];
    const float* skip1_b = (const float*)d_in[5];
    const float* c1_wl   = (const float*)d_in[6];
    const float* c1_bl   = (const float*)d_in[7];
    const float* c1_wr   = (const float*)d_in[8];
    const float* c1_br   = (const float*)d_in[9];
    const float* c1_we   = (const float*)d_in[10];
    const float* c1_att  = (const float*)d_in[11];
    const float* c1_bias = (const float*)d_in[12];
    const float* bn1_g   = (const float*)d_in[13];
    const float* bn1_b   = (const float*)d_in[14];
    const float* skip2_w = (const float*)d_in[15];
    const float* skip2_b = (const float*)d_in[16];
    const float* c2_wl   = (const float*)d_in[17];
    const float* c2_bl   = (const float*)d_in[18];
    const float* c2_wr   = (const float*)d_in[19];
    const float* c2_br   = (const float*)d_in[20];
    const float* c2_we   = (const float*)d_in[21];
    const float* c2_att  = (const float*)d_in[22];
    const float* c2_bias = (const float*)d_in[23];
    const float* bn2_g   = (const float*)d_in[24];
    const float* bn2_b   = (const float*)d_in[25];
    const float* cls_w   = (const float*)d_in[26];
    const float* cls_b   = (const float*)d_in[27];
    float* outp = (float*)d_out;

    float* ws = (float*)d_ws;
    size_t o = 0;
    float* A   = ws + o; o += 6400000;   // XL1P bf16 [n][128]; layer2: XL2P bf16 (lower) + xr2 fp32 (upper)
    float* B   = ws + o; o += 6400000;   // xr1 fp32 [n][128]
    float* Cb  = ws + o; o += 6400000;   // xp1 fp32 [n][128]
    float* D   = ws + o; o += 6400000;   // h1 pre-BN [n][128] ; later h2 pre-BN [n][64]
    int*   SRCS  = (int*)(ws + o); o += 800000;    // CSR-ordered src nodes
    u32*   EAHS  = (u32*)(ws + o); o += 6400000;   // CSR-ordered ea packed bf16 [E][8]
    u32*   XPx   = (u32*)(ws + o); o += 3200000;   // xp2 fp32 [n][64]
    u32*   WT1   = (u32*)(ws + o); o += 24576;     // [384][64]
    u32*   WT2   = (u32*)(ws + o); o += 12288;     // [192][64]
    // ---- contiguous zeroed region: COUNTS..PMAX (106784 u32) ----
    u32*   COUNTS  = (u32*)(ws + o); o += 50000;
    u32*   CURSORS = (u32*)(ws + o); o += 50000;
    float* STATS1  = ws + o; o += 256;
    float* STATS2  = ws + o; o += 128;
    float* PSUM    = ws + o; o += 3200;            // [G][64] pooled sum
    u32*   PMAX    = (u32*)(ws + o); o += 3200;    // [G][64] pooled max (monotonic enc)
    // ---- end zeroed region ----
    int*   ROWPTR  = (int*)(ws + o); o += 50016;
    u32*   BSUMS   = (u32*)(ws + o); o += 64;

    u16*   XL1P = (u16*)A;               // [n][128] bf16
    u16*   XL2P = (u16*)A;               // [n][64] bf16 (layer 2)
    float* xr2  = A + 3200000;
    float* xp2  = (float*)XPx;           // [n][64] fp32

    // zero COUNTS + CURSORS + STATS1 + STATS2 + PSUM + PMAX (contiguous, 106784 u32)
    zero_u32_kernel<<<(106784 + 255) / 256, 256, 0, stream>>>(COUNTS, 106784);
    // count_edges + wpack(WT1) + wpack(WT2) in one launch
    mega_prep_kernel<<<3269, 256, 0, stream>>>(ei, COUNTS,
        c1_wl, c1_wr, skip1_w, WT1, c2_wl, c2_wr, skip2_w, WT2);
    // scan part1 (49 blocks) runs concurrently with GEMM1 (782 blocks)
    scan1_gemm1_kernel<<<831, 256, 0, stream>>>(COUNTS, BSUMS, x, WT1,
        XL1P, B, Cb, c1_bl, c1_br, skip1_b, NN);
    scan_final_kernel<<<49, 256, 0, stream>>>(COUNTS, BSUMS, ROWPTR);
    scatter_pack_kernel<<<3125, 256, 0, stream>>>(ei, ea, ROWPTR, CURSORS, SRCS, EAHS);

    // ---- layer 1 ----
    gat1_fused_kernel<<<NN / 4, 256, 0, stream>>>((const u32*)XL1P, B, EAHS, SRCS, ROWPTR,
        c1_we, c1_att, c1_bias, D);
    bn_stats_kernel<128><<<98, 256, 0, stream>>>(D, STATS1);

    // ---- layer 2 (BN1-apply + skip + ELU fused into the GEMM staging) ----
    gemm2_fused_kernel<<<782, 256, 0, stream>>>(D, Cb, STATS1, bn1_g, bn1_b, WT2,
        XL2P, xr2, xp2, c2_bl, c2_br, skip2_b, NN);
    gat2_fused_kernel<<<NN / 4, 256, 0, stream>>>(XL2P, xr2, EAHS, SRCS, ROWPTR,
        c2_we, c2_att, c2_bias, D);
    bn_stats_kernel<64><<<98, 256, 0, stream>>>(D, STATS2);

    // ---- pool: wide atomic accumulate (BN2+skip+ELU fused) + tiny finalize/classify ----
    pool_acc_kernel<<<(NN + 127) / 128, 256, 0, stream>>>(D, xp2, STATS2, bn2_g, bn2_b,
        batch, PSUM, PMAX);
    pool_fin_kernel<<<GG, 64, 0, stream>>>(PSUM, PMAX, batch, cls_w, cls_b, outp);
}

// Round 8
// 545.725 us; speedup vs baseline: 1.1553x; 1.0127x over previous
//
#include <hip/hip_runtime.h>
#include <math.h>

#define NN 50000
#define NE 800000
#define GG 50

typedef unsigned int u32;
typedef unsigned short u16;
typedef float v2f __attribute__((ext_vector_type(2)));
typedef short bf16x8 __attribute__((ext_vector_type(8)));
typedef float f32x4 __attribute__((ext_vector_type(4)));

__device__ __forceinline__ float uaf(u32 x) { return __uint_as_float(x); }

__device__ __forceinline__ u32 bfpack2(float x, float y) {
    u32 a = __float_as_uint(x), b = __float_as_uint(y);
    a = (a + 0x7fffu + ((a >> 16) & 1u)) >> 16;
    b = (b + 0x7fffu + ((b >> 16) & 1u)) & 0xffff0000u;
    return b | a;
}
__device__ __forceinline__ u16 bf16of(float x) {
    u32 a = __float_as_uint(x);
    return (u16)((a + 0x7fffu + ((a >> 16) & 1u)) >> 16);
}

// monotonic float<->u32 encoding for atomicMax on floats
__device__ __forceinline__ u32 fenc(float x) {
    u32 u = __float_as_uint(x);
    return (u >> 31) ? ~u : (u | 0x80000000u);
}
__device__ __forceinline__ float fdec(u32 m) {
    return (m >> 31) ? uaf(m & 0x7fffffffu) : uaf(~m);
}

// packed fp32 math (v_pk_fma_f32 / v_pk_max_f32 on gfx950)
__device__ __forceinline__ v2f fma2(v2f a, v2f b, v2f c) { return __builtin_elementwise_fma(a, b, c); }
__device__ __forceinline__ v2f max2(v2f a, v2f b) { return __builtin_elementwise_max(a, b); }

// DPP partial reductions (VALU pipe). ctrl must be an immediate.
template <int CTRL>
__device__ __forceinline__ float dpp_add(float v) {
    int t = __builtin_amdgcn_update_dpp(0, __float_as_int(v), CTRL, 0xf, 0xf, true);
    return v + __int_as_float(t);
}
__device__ __forceinline__ float swz_xor16_add(float v) {
    int t = __builtin_amdgcn_ds_swizzle(__float_as_int(v), 0x401F);
    return v + __int_as_float(t);
}
// after RED4+xor16: each 32-group holds its sum; total = group0 + group1 (uniform)
__device__ __forceinline__ float total64(float v) {
    return __int_as_float(__builtin_amdgcn_readlane(__float_as_int(v), 0))
         + __int_as_float(__builtin_amdgcn_readlane(__float_as_int(v), 32));
}
#define RED4_STAGES(q)  do {                                                    \
    _Pragma("unroll") for (int j = 0; j < 4; ++j) q[j] = dpp_add<0xB1>(q[j]);  \
    _Pragma("unroll") for (int j = 0; j < 4; ++j) q[j] = dpp_add<0x4E>(q[j]);  \
    _Pragma("unroll") for (int j = 0; j < 4; ++j) q[j] = dpp_add<0x141>(q[j]); \
    _Pragma("unroll") for (int j = 0; j < 4; ++j) q[j] = dpp_add<0x140>(q[j]); \
} while (0)

// ---------------- utility ----------------
__global__ void zero_u32_kernel(u32* __restrict__ p, int n) {
    int i = blockIdx.x * 256 + threadIdx.x;
    if (i < n) p[i] = 0u;
}

// ---------------- mega prep: count_edges + wpack(WT1) + wpack(WT2) ----------------
__global__ __launch_bounds__(256) void mega_prep_kernel(
    const int* __restrict__ ei, u32* __restrict__ counts,
    const float* __restrict__ w1a, const float* __restrict__ w1b, const float* __restrict__ w1c,
    u32* __restrict__ WT1,
    const float* __restrict__ w2a, const float* __restrict__ w2b, const float* __restrict__ w2c,
    u32* __restrict__ WT2)
{
    int b = blockIdx.x;
    int t = threadIdx.x;
    if (b < 3125) {
        int e = b * 256 + t;
        if (e < NE) atomicAdd(&counts[ei[NE + e]], 1u);
    } else if (b < 3125 + 96) {
        int i = (b - 3125) * 256 + t;           // 0 .. 3*128*64-1
        const int per = 128 * 64;
        int mat = i / per;
        int r = i - mat * per;
        const float* W = (mat == 0) ? w1a : (mat == 1) ? w1b : w1c;
        int col = r >> 6, c = r & 63;
        WT1[i] = bfpack2(W[(size_t)(2 * c) * 128 + col], W[(size_t)(2 * c + 1) * 128 + col]);
    } else {
        int i = (b - 3221) * 256 + t;           // 0 .. 3*64*64-1
        const int per = 64 * 64;
        int mat = i / per;
        int r = i - mat * per;
        const float* W = (mat == 0) ? w2a : (mat == 1) ? w2b : w2c;
        int col = r >> 6, c = r & 63;
        WT2[i] = bfpack2(W[(size_t)(2 * c) * 64 + col], W[(size_t)(2 * c + 1) * 64 + col]);
    }
}

// ---------------- scan part1 (blocks 0-48) + GEMM1 (blocks 49+) ----------------
__global__ __launch_bounds__(256) void scan1_gemm1_kernel(
    const u32* __restrict__ counts, u32* __restrict__ bsums,
    const float* __restrict__ X, const u32* __restrict__ Wt,
    u16* __restrict__ out0, float* __restrict__ out1, float* __restrict__ out2,
    const float* __restrict__ b0, const float* __restrict__ b1, const float* __restrict__ b2,
    int n)
{
    __shared__ __align__(16) u32 SMEM[64 * 68 * 2];
    int t = threadIdx.x;
    if (blockIdx.x < 49) {
        u32* ls = SMEM;
        int base = blockIdx.x * 1024 + t * 4;
        u32 s = 0;
#pragma unroll
        for (int j = 0; j < 4; ++j) { int idx = base + j; if (idx < NN) s += counts[idx]; }
        ls[t] = s;
        __syncthreads();
        for (int off = 128; off > 0; off >>= 1) {
            if (t < off) ls[t] += ls[t + off];
            __syncthreads();
        }
        if (t == 0) bsums[blockIdx.x] = ls[0];
        return;
    }
    u32* Xs = SMEM;
    u32* Ws = SMEM + 64 * 68;
    int row0 = (blockIdx.x - 49) * 64;
#pragma unroll
    for (int i = 0; i < 16; ++i) {
        int flat = t + 256 * i;
        int r = flat >> 6, c = flat & 63;
        int gr = row0 + r;
        u32 v = 0u;
        if (gr < n) {
            float2 f = *(const float2*)(X + (size_t)gr * 128 + c * 2);
            v = bfpack2(f.x, f.y);
        }
        Xs[r * 68 + c] = v;
    }
    int w = t >> 6, lane = t & 63;
    int l15 = lane & 15, quad = lane >> 4;
    for (int nb = 0; nb < 6; ++nb) {
#pragma unroll
        for (int i = 0; i < 16; ++i) {
            int flat = t + 256 * i;
            int cc = flat >> 6, c = flat & 63;
            Ws[cc * 68 + c] = Wt[(size_t)(nb * 64 + cc) * 64 + c];
        }
        __syncthreads();
        f32x4 acc[4] = {};
#pragma unroll
        for (int kk = 0; kk < 4; ++kk) {
            bf16x8 af = *(const bf16x8*)&Xs[(w * 16 + l15) * 68 + kk * 16 + quad * 4];
#pragma unroll
            for (int j = 0; j < 4; ++j) {
                bf16x8 bf = *(const bf16x8*)&Ws[(j * 16 + l15) * 68 + kk * 16 + quad * 4];
                acc[j] = __builtin_amdgcn_mfma_f32_16x16x32_bf16(af, bf, acc[j], 0, 0, 0);
            }
        }
        int mat = nb >> 1;
        int col0 = (nb & 1) * 64;
        const float* bp = (mat == 0) ? b0 : (mat == 1) ? b1 : b2;
#pragma unroll
        for (int j = 0; j < 4; ++j) {
            int col = col0 + j * 16 + l15;
            float bb = bp[col];
#pragma unroll
            for (int r = 0; r < 4; ++r) {
                int grow = row0 + w * 16 + quad * 4 + r;
                if (grow < n) {
                    float v = acc[j][r] + bb;
                    if (mat == 0) out0[(size_t)grow * 128 + col] = bf16of(v);
                    else if (mat == 1) out1[(size_t)grow * 128 + col] = v;
                    else out2[(size_t)grow * 128 + col] = v;
                }
            }
        }
        __syncthreads();
    }
}

// ---------------- scan final (block-sum scan inlined as a wave scan) ----------------
__global__ __launch_bounds__(256) void scan_final_kernel(
    const u32* __restrict__ counts, const u32* __restrict__ bsums, int* __restrict__ rowptr)
{
    __shared__ u32 ls[256];
    __shared__ u32 prefsh;
    int t = threadIdx.x;
    if (t < 64) {
        u32 v = (t < 49) ? bsums[t] : 0u;
#pragma unroll
        for (int off = 1; off < 64; off <<= 1) {
            u32 tv = __shfl_up(v, off, 64);
            if (t >= off) v += tv;
        }
        u32 ex = __shfl_up(v, 1, 64);
        if (t == 0) ex = 0u;
        if (t == (int)blockIdx.x) prefsh = ex;
    }
    __syncthreads();
    u32 bpref = prefsh;
    int base = blockIdx.x * 1024 + t * 4;
    u32 c[4];
    u32 s = 0;
#pragma unroll
    for (int j = 0; j < 4; ++j) { int idx = base + j; c[j] = (idx < NN) ? counts[idx] : 0u; s += c[j]; }
    ls[t] = s;
    __syncthreads();
    for (int off = 1; off < 256; off <<= 1) {
        u32 add = (t >= off) ? ls[t - off] : 0u;
        __syncthreads();
        ls[t] += add;
        __syncthreads();
    }
    u32 run = ls[t] - s + bpref;
#pragma unroll
    for (int j = 0; j < 4; ++j) { int idx = base + j; if (idx < NN) { rowptr[idx] = (int)run; } run += c[j]; }
    if (blockIdx.x == 0 && t == 0) rowptr[NN] = NE;
}

// ---------------- scatter: CSR-order srcs + CSR-order packed edge attrs ----------------
__global__ __launch_bounds__(256) void scatter_pack_kernel(
    const int* __restrict__ ei, const float* __restrict__ ea, const int* __restrict__ rowptr,
    u32* __restrict__ cursors, int* __restrict__ srcs, u32* __restrict__ eahs)
{
    int e = blockIdx.x * 256 + threadIdx.x;
    if (e < NE) {
        int sn = ei[e];
        int d = ei[NE + e];
        u32 pos = atomicAdd(&cursors[d], 1u);
        int slot = rowptr[d] + (int)pos;
        srcs[slot] = sn;
        const float4* s4 = (const float4*)(ea + (size_t)e * 16);
        float4 f0 = s4[0], f1 = s4[1], f2 = s4[2], f3 = s4[3];
        uint4 o0 = {bfpack2(f0.x, f0.y), bfpack2(f0.z, f0.w), bfpack2(f1.x, f1.y), bfpack2(f1.z, f1.w)};
        uint4 o1 = {bfpack2(f2.x, f2.y), bfpack2(f2.z, f2.w), bfpack2(f3.x, f3.y), bfpack2(f3.z, f3.w)};
        *(uint4*)(eahs + (size_t)slot * 8) = o0;
        *(uint4*)(eahs + (size_t)slot * 8 + 4) = o1;
    }
}

// ---------------- fused GATv2 layer 1 (H=2, C=64) ----------------
// 2-deep software pipeline: load block for group g+1 issued BEFORE compute of
// group g, pinned with sched_barrier(0) (asm "memory" clobber was insufficient:
// compiler sank the loads — VGPR_Count=32 proved no buffer was live).
__global__ __launch_bounds__(256) void gat1_fused_kernel(
    const u32* __restrict__ xlp, const float* __restrict__ xr,
    const u32* __restrict__ eahs, const int* __restrict__ srcs,
    const int* __restrict__ rowptr, const float* __restrict__ We,
    const float* __restrict__ att, const float* __restrict__ bias,
    float* __restrict__ out)
{
    int lane = threadIdx.x & 63;
    int d = (blockIdx.x * 256 + threadIdx.x) >> 6;
    if (d >= NN) return;
    int du = __builtin_amdgcn_readfirstlane(d);
    int beg = rowptr[du], end = rowptr[du + 1];
    int c0 = lane * 2;
    v2f w[16];
#pragma unroll
    for (int k = 0; k < 16; ++k) {
        float2 t2 = *(const float2*)(We + k * 128 + c0);
        w[k] = (v2f){t2.x, t2.y};
    }
    float at0 = att[c0], at1 = att[c0 + 1];
    float2 bt = *(const float2*)(bias + c0);
    float2 xq = *(const float2*)(xr + (size_t)du * 128 + c0);
    v2f xrv = {xq.x, xq.y};

    float s = 0.f;
    v2f acc = {0.f, 0.f};

    int cnt = (end - beg) >> 2;
    int sA[4]; uint4 eA0[4], eA1[4]; u32 xA[4];
    int sB[4]; uint4 eB0[4], eB1[4]; u32 xB[4];

#define G1_LOAD(SN, E0, E1, X, base_) do {                                     \
    _Pragma("unroll")                                                          \
    for (int j = 0; j < 4; ++j) SN[j] = srcs[(base_) + j];                     \
    _Pragma("unroll")                                                          \
    for (int j = 0; j < 4; ++j) {                                              \
        const uint4* e4_ = (const uint4*)(eahs + (size_t)((base_) + j) * 8);   \
        E0[j] = e4_[0]; E1[j] = e4_[1];                                        \
    }                                                                          \
    _Pragma("unroll")                                                          \
    for (int j = 0; j < 4; ++j) X[j] = xlp[(size_t)SN[j] * 64 + lane];         \
    __builtin_amdgcn_sched_barrier(0);                                         \
} while (0)

#define G1_PROC(E0, E1, X) do {                                                \
    float q[4]; v2f xv[4];                                                     \
    _Pragma("unroll")                                                          \
    for (int j = 0; j < 4; ++j) {                                              \
        u32 ew[8] = {E0[j].x, E0[j].y, E0[j].z, E0[j].w,                       \
                     E1[j].x, E1[j].y, E1[j].z, E1[j].w};                      \
        v2f e = {0.f, 0.f};                                                    \
        _Pragma("unroll")                                                      \
        for (int kk = 0; kk < 8; ++kk) {                                       \
            u32 pk = ew[kk];                                                   \
            float s1 = uaf(pk << 16), s2 = uaf(pk & 0xffff0000u);              \
            e = fma2(w[2 * kk],     (v2f){s1, s1}, e);                         \
            e = fma2(w[2 * kk + 1], (v2f){s2, s2}, e);                         \
        }                                                                      \
        u32 pxv = X[j];                                                        \
        xv[j] = (v2f){uaf(pxv << 16), uaf(pxv & 0xffff0000u)};                 \
        v2f mm = xv[j] + xrv + e;                                              \
        v2f lk = max2(mm, mm * 0.2f);                                          \
        q[j] = fmaf(lk.x, at0, lk.y * at1);                                    \
    }                                                                          \
    RED4_STAGES(q);                                                            \
    _Pragma("unroll")                                                          \
    for (int j = 0; j < 4; ++j) q[j] = swz_xor16_add(q[j]);                    \
    float w0 = __expf(q[0]), w1 = __expf(q[1]);                                \
    float w2 = __expf(q[2]), w3 = __expf(q[3]);                                \
    s += (w0 + w1) + (w2 + w3);                                                \
    acc = fma2(xv[0], (v2f){w0, w0}, acc);                                     \
    acc = fma2(xv[1], (v2f){w1, w1}, acc);                                     \
    acc = fma2(xv[2], (v2f){w2, w2}, acc);                                     \
    acc = fma2(xv[3], (v2f){w3, w3}, acc);                                     \
} while (0)

    if (cnt > 0) {
        G1_LOAD(sA, eA0, eA1, xA, beg);
        int g = 0;
        for (; g + 2 <= cnt; g += 2) {
            G1_LOAD(sB, eB0, eB1, xB, beg + (g + 1) * 4);
            G1_PROC(eA0, eA1, xA);
            if (g + 2 < cnt) G1_LOAD(sA, eA0, eA1, xA, beg + (g + 2) * 4);
            G1_PROC(eB0, eB1, xB);
        }
        if (g < cnt) G1_PROC(eA0, eA1, xA);
    }
#undef G1_LOAD
#undef G1_PROC
    for (int i = beg + cnt * 4; i < end; ++i) {
        const uint4* e4 = (const uint4*)(eahs + (size_t)i * 8);
        uint4 ql = e4[0], qh = e4[1];
        u32 er[8] = {ql.x, ql.y, ql.z, ql.w, qh.x, qh.y, qh.z, qh.w};
        int sn = srcs[i];
        u32 px = xlp[(size_t)sn * 64 + lane];
        v2f e = {0.f, 0.f};
#pragma unroll
        for (int kk = 0; kk < 8; ++kk) {
            u32 pk = er[kk];
            float s1 = uaf(pk << 16), s2 = uaf(pk & 0xffff0000u);
            e = fma2(w[2 * kk],     (v2f){s1, s1}, e);
            e = fma2(w[2 * kk + 1], (v2f){s2, s2}, e);
        }
        v2f xv = {uaf(px << 16), uaf(px & 0xffff0000u)};
        v2f mm = xv + xrv + e;
        v2f lk = max2(mm, mm * 0.2f);
        float p = fmaf(lk.x, at0, lk.y * at1);
        p = dpp_add<0xB1>(p);
        p = dpp_add<0x4E>(p);
        p = dpp_add<0x141>(p);
        p = dpp_add<0x140>(p);
        p = swz_xor16_add(p);
        float ww = __expf(p);
        s += ww;
        acc = fma2(xv, (v2f){ww, ww}, acc);
    }
    float inv = 1.f / (s + 1e-16f);
    float2 o;
    o.x = fmaf(acc.x, inv, bt.x);
    o.y = fmaf(acc.y, inv, bt.y);
    *(float2*)(out + (size_t)d * 128 + c0) = o;
}

// ---------------- fused GATv2 layer 2 (H=1, C=64) ----------------
__global__ __launch_bounds__(256) void gat2_fused_kernel(
    const u16* __restrict__ xlp, const float* __restrict__ xr,
    const u32* __restrict__ eahs, const int* __restrict__ srcs,
    const int* __restrict__ rowptr, const float* __restrict__ We,
    const float* __restrict__ att, const float* __restrict__ bias,
    float* __restrict__ out)
{
    int lane = threadIdx.x & 63;
    int d = (blockIdx.x * 256 + threadIdx.x) >> 6;
    if (d >= NN) return;
    int du = __builtin_amdgcn_readfirstlane(d);
    int beg = rowptr[du], end = rowptr[du + 1];
    float w[16];
#pragma unroll
    for (int k = 0; k < 16; ++k) w[k] = We[k * 64 + lane];
    float at0 = att[lane];
    float bb = bias[lane];
    float xrv = xr[(size_t)du * 64 + lane];

    float s = 0.f, acc = 0.f;

    int cnt = (end - beg) >> 2;
    int sA[4]; uint4 eA0[4], eA1[4]; float xA[4];
    int sB[4]; uint4 eB0[4], eB1[4]; float xB[4];

#define G2_LOAD(SN, E0, E1, X, base_) do {                                     \
    _Pragma("unroll")                                                          \
    for (int j = 0; j < 4; ++j) SN[j] = srcs[(base_) + j];                     \
    _Pragma("unroll")                                                          \
    for (int j = 0; j < 4; ++j) {                                              \
        const uint4* e4_ = (const uint4*)(eahs + (size_t)((base_) + j) * 8);   \
        E0[j] = e4_[0]; E1[j] = e4_[1];                                        \
    }                                                                          \
    _Pragma("unroll")                                                          \
    for (int j = 0; j < 4; ++j)                                                \
        X[j] = uaf((u32)xlp[(size_t)SN[j] * 64 + lane] << 16);                 \
    __builtin_amdgcn_sched_barrier(0);                                         \
} while (0)

#define G2_PROC(E0, E1, X) do {                                                \
    float q[4];                                                                \
    _Pragma("unroll")                                                          \
    for (int j = 0; j < 4; ++j) {                                              \
        u32 ew[8] = {E0[j].x, E0[j].y, E0[j].z, E0[j].w,                       \
                     E1[j].x, E1[j].y, E1[j].z, E1[j].w};                      \
        float e = 0.f;                                                         \
        _Pragma("unroll")                                                      \
        for (int kk = 0; kk < 8; ++kk) {                                       \
            u32 pk = ew[kk];                                                   \
            float s1 = uaf(pk << 16), s2 = uaf(pk & 0xffff0000u);              \
            e = fmaf(s1, w[2 * kk], e);                                        \
            e = fmaf(s2, w[2 * kk + 1], e);                                    \
        }                                                                      \
        float mm = X[j] + xrv + e;                                             \
        mm = fmaxf(mm, 0.2f * mm);                                             \
        q[j] = mm * at0;                                                       \
    }                                                                          \
    RED4_STAGES(q);                                                            \
    _Pragma("unroll")                                                          \
    for (int j = 0; j < 4; ++j) { q[j] = swz_xor16_add(q[j]); q[j] = total64(q[j]); } \
    float w0 = __expf(q[0]), w1 = __expf(q[1]);                                \
    float w2 = __expf(q[2]), w3 = __expf(q[3]);                                \
    s += (w0 + w1) + (w2 + w3);                                                \
    acc += fmaf(w0, X[0], fmaf(w1, X[1], fmaf(w2, X[2], w3 * X[3])));          \
} while (0)

    if (cnt > 0) {
        G2_LOAD(sA, eA0, eA1, xA, beg);
        int g = 0;
        for (; g + 2 <= cnt; g += 2) {
            G2_LOAD(sB, eB0, eB1, xB, beg + (g + 1) * 4);
            G2_PROC(eA0, eA1, xA);
            if (g + 2 < cnt) G2_LOAD(sA, eA0, eA1, xA, beg + (g + 2) * 4);
            G2_PROC(eB0, eB1, xB);
        }
        if (g < cnt) G2_PROC(eA0, eA1, xA);
    }
#undef G2_LOAD
#undef G2_PROC
    for (int i = beg + cnt * 4; i < end; ++i) {
        const uint4* e4 = (const uint4*)(eahs + (size_t)i * 8);
        uint4 ql = e4[0], qh = e4[1];
        u32 er[8] = {ql.x, ql.y, ql.z, ql.w, qh.x, qh.y, qh.z, qh.w};
        int sn = srcs[i];
        float xv = uaf((u32)xlp[(size_t)sn * 64 + lane] << 16);
        float e = 0.f;
#pragma unroll
        for (int kk = 0; kk < 8; ++kk) {
            u32 pk = er[kk];
            float s1 = uaf(pk << 16), s2 = uaf(pk & 0xffff0000u);
            e = fmaf(s1, w[2 * kk], e);
            e = fmaf(s2, w[2 * kk + 1], e);
        }
        float mm = xv + xrv + e;
        mm = fmaxf(mm, 0.2f * mm);
        float p = mm * at0;
        p = dpp_add<0xB1>(p);
        p = dpp_add<0x4E>(p);
        p = dpp_add<0x141>(p);
        p = dpp_add<0x140>(p);
        p = swz_xor16_add(p);
        p = total64(p);
        float ww = __expf(p);
        s += ww;
        acc = fmaf(ww, xv, acc);
    }
    out[(size_t)d * 64 + lane] = acc / (s + 1e-16f) + bb;
}

// ---------------- fused MFMA GEMM, layer 2 (BN1+skip+ELU+pack in staging) ----------------
__global__ __launch_bounds__(256) void gemm2_fused_kernel(
    const float* __restrict__ H, const float* __restrict__ XPin,
    const float* __restrict__ stats, const float* __restrict__ bg, const float* __restrict__ bbv,
    const u32* __restrict__ Wt,
    u16* __restrict__ out0, float* __restrict__ out1, float* __restrict__ out2,
    const float* __restrict__ b0, const float* __restrict__ b1, const float* __restrict__ b2,
    int n)
{
    __shared__ __align__(16) u32 Xs[64 * 68];
    __shared__ __align__(16) u32 Ws[64 * 68];
    int t = threadIdx.x;
    int row0 = blockIdx.x * 64;
    int c = t & 63;
    int ch0 = 2 * c, ch1 = ch0 + 1;
    float mu0 = stats[ch0] * (1.f / NN), mu1 = stats[ch1] * (1.f / NN);
    float var0 = stats[128 + ch0] * (1.f / NN) - mu0 * mu0;
    float var1 = stats[128 + ch1] * (1.f / NN) - mu1 * mu1;
    float s0 = rsqrtf(var0 + 1e-5f) * bg[ch0];
    float s1 = rsqrtf(var1 + 1e-5f) * bg[ch1];
    float t0 = bbv[ch0] - mu0 * s0;
    float t1 = bbv[ch1] - mu1 * s1;
#pragma unroll
    for (int i = 0; i < 16; ++i) {
        int flat = t + 256 * i;
        int r = flat >> 6;
        int gr = row0 + r;
        u32 v = 0u;
        if (gr < n) {
            float2 hv = *(const float2*)(H + (size_t)gr * 128 + ch0);
            float2 xv = *(const float2*)(XPin + (size_t)gr * 128 + ch0);
            float v0 = fmaf(hv.x, s0, t0) + xv.x;
            float v1 = fmaf(hv.y, s1, t1) + xv.y;
            v0 = (v0 > 0.f) ? v0 : expm1f(v0);
            v1 = (v1 > 0.f) ? v1 : expm1f(v1);
            v = bfpack2(v0, v1);
        }
        Xs[r * 68 + c] = v;
    }
    int w = t >> 6, lane = t & 63;
    int l15 = lane & 15, quad = lane >> 4;
    for (int nb = 0; nb < 3; ++nb) {
#pragma unroll
        for (int i = 0; i < 16; ++i) {
            int flat = t + 256 * i;
            int cc = flat >> 6, cw = flat & 63;
            Ws[cc * 68 + cw] = Wt[(size_t)(nb * 64 + cc) * 64 + cw];
        }
        __syncthreads();
        f32x4 acc[4] = {};
#pragma unroll
        for (int kk = 0; kk < 4; ++kk) {
            bf16x8 af = *(const bf16x8*)&Xs[(w * 16 + l15) * 68 + kk * 16 + quad * 4];
#pragma unroll
            for (int j = 0; j < 4; ++j) {
                bf16x8 bf = *(const bf16x8*)&Ws[(j * 16 + l15) * 68 + kk * 16 + quad * 4];
                acc[j] = __builtin_amdgcn_mfma_f32_16x16x32_bf16(af, bf, acc[j], 0, 0, 0);
            }
        }
        const float* bp = (nb == 0) ? b0 : (nb == 1) ? b1 : b2;
#pragma unroll
        for (int j = 0; j < 4; ++j) {
            int col = j * 16 + l15;
            float bb = bp[col];
#pragma unroll
            for (int r = 0; r < 4; ++r) {
                int grow = row0 + w * 16 + quad * 4 + r;
                if (grow < n) {
                    float v = acc[j][r] + bb;
                    if (nb == 0) out0[(size_t)grow * 64 + col] = bf16of(v);
                    else if (nb == 1) out1[(size_t)grow * 64 + col] = v;
                    else out2[(size_t)grow * 64 + col] = v;
                }
            }
        }
        __syncthreads();
    }
}

// ---------------- batch-norm stats ----------------
template <int C>
__global__ __launch_bounds__(256) void bn_stats_kernel(const float* __restrict__ h, float* __restrict__ stats) {
    const int SUB = 256 / C;
    int t = threadIdx.x;
    int c = t & (C - 1);
    int rs = t / C;
    int r0 = blockIdx.x * 512;
    int r1 = min(NN, r0 + 512);
    float s = 0.f, s2 = 0.f;
    for (int r = r0 + rs; r < r1; r += SUB) {
        float v = h[(size_t)r * C + c];
        s += v; s2 = fmaf(v, v, s2);
    }
    __shared__ float ls[256], ls2[256];
    ls[t] = s; ls2[t] = s2;
    __syncthreads();
    if (rs == 0) {
        for (int j = 1; j < SUB; ++j) { s += ls[j * C + c]; s2 += ls2[j * C + c]; }
        atomicAdd(&stats[c], s);
        atomicAdd(&stats[C + c], s2);
    }
}

// ---------------- pool accumulate: BN2+skip+ELU fused, per-graph atomic sum/max ----------------
__global__ __launch_bounds__(256) void pool_acc_kernel(
    const float* __restrict__ D, const float* __restrict__ xp2,
    const float* __restrict__ stats, const float* __restrict__ bg, const float* __restrict__ bbv,
    const int* __restrict__ batch,
    float* __restrict__ psum, u32* __restrict__ pmax)
{
    int t = threadIdx.x;
    int lane = t & 63, rs = t >> 6;
    float mu = stats[lane] * (1.f / NN);
    float var = stats[64 + lane] * (1.f / NN) - mu * mu;
    float sc = rsqrtf(var + 1e-5f) * bg[lane];
    float tb = bbv[lane] - mu * sc;
    int r0 = blockIdx.x * 128;
    int r1 = min(NN, r0 + 128);
    int curg = -1;
    float sum = 0.f, mx = -INFINITY;
    for (int r = r0 + rs; r < r1; r += 4) {
        int g = batch[r];               // wave-uniform (lane indexes channel only)
        if (g != curg) {
            if (curg >= 0) {
                atomicAdd(&psum[curg * 64 + lane], sum);
                atomicMax(&pmax[curg * 64 + lane], fenc(mx));
            }
            curg = g; sum = 0.f; mx = -INFINITY;
        }
        float v = fmaf(D[(size_t)r * 64 + lane], sc, tb) + xp2[(size_t)r * 64 + lane];
        v = (v > 0.f) ? v : expm1f(v);
        sum += v; mx = fmaxf(mx, v);
    }
    if (curg >= 0) {
        atomicAdd(&psum[curg * 64 + lane], sum);
        atomicMax(&pmax[curg * 64 + lane], fenc(mx));
    }
}

// ---------------- pool finalize + classifier (tiny) ----------------
__global__ __launch_bounds__(64) void pool_fin_kernel(
    const float* __restrict__ psum, const u32* __restrict__ pmax,
    const int* __restrict__ batch,
    const float* __restrict__ cw, const float* __restrict__ cb,
    float* __restrict__ outp)
{
    int g = blockIdx.x;
    int lane = threadIdx.x;
    int lo = 0, hi = NN;
    while (lo < hi) { int mid = (lo + hi) >> 1; if (batch[mid] < g) lo = mid + 1; else hi = mid; }
    int s0 = lo;
    hi = NN;
    while (lo < hi) { int mid = (lo + hi) >> 1; if (batch[mid] < g + 1) lo = mid + 1; else hi = mid; }
    int e0 = lo;
    float cnt = (float)(e0 - s0);
    float mean = psum[g * 64 + lane] / fmaxf(cnt, 1.f);
    float mx = fdec(pmax[g * 64 + lane]);
#pragma unroll
    for (int c = 0; c < 2; ++c) {
        float v = fmaf(mean, cw[lane * 2 + c], mx * cw[(64 + lane) * 2 + c]);
        v = dpp_add<0xB1>(v);
        v = dpp_add<0x4E>(v);
        v = dpp_add<0x141>(v);
        v = dpp_add<0x140>(v);
        v = swz_xor16_add(v);
        v = total64(v);
        if (lane == 0) outp[g * 2 + c] = v + cb[c];
    }
}

extern "C" void kernel_launch(void* const* d_in, const int* in_sizes, int n_in,
                              void* d_out, int out_size, void* d_ws, size_t ws_size,
                              hipStream_t stream)
{
    const float* x       = (const float*)d_in[0];
    const int*   ei      = (const int*)d_in[1];
    const float* ea      = (const float*)d_in[2];
    const int*   batch   = (const int*)d_in[3];
    const float* skip1_w = (const float*)d_in[4];
    const float* skip1_b = (const float*)d_in[5];
    const float* c1_wl   = (const float*)d_in[6];
    const float* c1_bl   = (const float*)d_in[7];
    const float* c1_wr   = (const float*)d_in[8];
    const float* c1_br   = (const float*)d_in[9];
    const float* c1_we   = (const float*)d_in[10];
    const float* c1_att  = (const float*)d_in[11];
    const float* c1_bias = (const float*)d_in[12];
    const float* bn1_g   = (const float*)d_in[13];
    const float* bn1_b   = (const float*)d_in[14];
    const float* skip2_w = (const float*)d_in[15];
    const float* skip2_b = (const float*)d_in[16];
    const float* c2_wl   = (const float*)d_in[17];
    const float* c2_bl   = (const float*)d_in[18];
    const float* c2_wr   = (const float*)d_in[19];
    const float* c2_br   = (const float*)d_in[20];
    const float* c2_we   = (const float*)d_in[21];
    const float* c2_att  = (const float*)d_in[22];
    const float* c2_bias = (const float*)d_in[23];
    const float* bn2_g   = (const float*)d_in[24];
    const float* bn2_b   = (const float*)d_in[25];
    const float* cls_w   = (const float*)d_in[26];
    const float* cls_b   = (const float*)d_in[27];
    float* outp = (float*)d_out;

    float* ws = (float*)d_ws;
    size_t o = 0;
    float* A   = ws + o; o += 6400000;   // XL1P bf16 [n][128]; layer2: XL2P bf16 (lower) + xr2 fp32 (upper)
    float* B   = ws + o; o += 6400000;   // xr1 fp32 [n][128]
    float* Cb  = ws + o; o += 6400000;   // xp1 fp32 [n][128]
    float* D   = ws + o; o += 6400000;   // h1 pre-BN [n][128] ; later h2 pre-BN [n][64]
    int*   SRCS  = (int*)(ws + o); o += 800000;    // CSR-ordered src nodes
    u32*   EAHS  = (u32*)(ws + o); o += 6400000;   // CSR-ordered ea packed bf16 [E][8]
    u32*   XPx   = (u32*)(ws + o); o += 3200000;   // xp2 fp32 [n][64]
    u32*   WT1   = (u32*)(ws + o); o += 24576;     // [384][64]
    u32*   WT2   = (u32*)(ws + o); o += 12288;     // [192][64]
    // ---- contiguous zeroed region: COUNTS..PMAX (106784 u32) ----
    u32*   COUNTS  = (u32*)(ws + o); o += 50000;
    u32*   CURSORS = (u32*)(ws + o); o += 50000;
    float* STATS1  = ws + o; o += 256;
    float* STATS2  = ws + o; o += 128;
    float* PSUM    = ws + o; o += 3200;            // [G][64] pooled sum
    u32*   PMAX    = (u32*)(ws + o); o += 3200;    // [G][64] pooled max (monotonic enc)
    // ---- end zeroed region ----
    int*   ROWPTR  = (int*)(ws + o); o += 50016;
    u32*   BSUMS   = (u32*)(ws + o); o += 64;

    u16*   XL1P = (u16*)A;               // [n][128] bf16
    u16*   XL2P = (u16*)A;               // [n][64] bf16 (layer 2)
    float* xr2  = A + 3200000;
    float* xp2  = (float*)XPx;           // [n][64] fp32

    // zero COUNTS + CURSORS + STATS1 + STATS2 + PSUM + PMAX (contiguous, 106784 u32)
    zero_u32_kernel<<<(106784 + 255) / 256, 256, 0, stream>>>(COUNTS, 106784);
    // count_edges + wpack(WT1) + wpack(WT2) in one launch
    mega_prep_kernel<<<3269, 256, 0, stream>>>(ei, COUNTS,
        c1_wl, c1_wr, skip1_w, WT1, c2_wl, c2_wr, skip2_w, WT2);
    // scan part1 (49 blocks) runs concurrently with GEMM1 (782 blocks)
    scan1_gemm1_kernel<<<831, 256, 0, stream>>>(COUNTS, BSUMS, x, WT1,
        XL1P, B, Cb, c1_bl, c1_br, skip1_b, NN);
    scan_final_kernel<<<49, 256, 0, stream>>>(COUNTS, BSUMS, ROWPTR);
    scatter_pack_kernel<<<3125, 256, 0, stream>>>(ei, ea, ROWPTR, CURSORS, SRCS, EAHS);

    // ---- layer 1 ----
    gat1_fused_kernel<<<NN / 4, 256, 0, stream>>>((const u32*)XL1P, B, EAHS, SRCS, ROWPTR,
        c1_we, c1_att, c1_bias, D);
    bn_stats_kernel<128><<<98, 256, 0, stream>>>(D, STATS1);

    // ---- layer 2 (BN1-apply + skip + ELU fused into the GEMM staging) ----
    gemm2_fused_kernel<<<782, 256, 0, stream>>>(D, Cb, STATS1, bn1_g, bn1_b, WT2,
        XL2P, xr2, xp2, c2_bl, c2_br, skip2_b, NN);
    gat2_fused_kernel<<<NN / 4, 256, 0, stream>>>(XL2P, xr2, EAHS, SRCS, ROWPTR,
        c2_we, c2_att, c2_bias, D);
    bn_stats_kernel<64><<<98, 256, 0, stream>>>(D, STATS2);

    // ---- pool: wide atomic accumulate (BN2+skip+ELU fused) + tiny finalize/classify ----
    pool_acc_kernel<<<(NN + 127) / 128, 256, 0, stream>>>(D, xp2, STATS2, bn2_g, bn2_b,
        batch, PSUM, PMAX);
    pool_fin_kernel<<<GG, 64, 0, stream>>>(PSUM, PMAX, batch, cls_w, cls_b, outp);
}

// Round 14
// 517.388 us; speedup vs baseline: 1.2185x; 1.0548x over previous
//
#include <hip/hip_runtime.h>
#include <math.h>

#define NN 50000
#define NE 800000
#define GG 50

typedef unsigned int u32;
typedef unsigned short u16;
typedef float v2f __attribute__((ext_vector_type(2)));
typedef short bf16x8 __attribute__((ext_vector_type(8)));
typedef float f32x4 __attribute__((ext_vector_type(4)));

__device__ __forceinline__ float uaf(u32 x) { return __uint_as_float(x); }

__device__ __forceinline__ u32 bfpack2(float x, float y) {
    u32 a = __float_as_uint(x), b = __float_as_uint(y);
    a = (a + 0x7fffu + ((a >> 16) & 1u)) >> 16;
    b = (b + 0x7fffu + ((b >> 16) & 1u)) & 0xffff0000u;
    return b | a;
}
__device__ __forceinline__ u16 bf16of(float x) {
    u32 a = __float_as_uint(x);
    return (u16)((a + 0x7fffu + ((a >> 16) & 1u)) >> 16);
}

// monotonic float<->u32 encoding for atomicMax on floats
__device__ __forceinline__ u32 fenc(float x) {
    u32 u = __float_as_uint(x);
    return (u >> 31) ? ~u : (u | 0x80000000u);
}
__device__ __forceinline__ float fdec(u32 m) {
    return (m >> 31) ? uaf(m & 0x7fffffffu) : uaf(~m);
}

// packed fp32 math (v_pk_fma_f32 / v_pk_max_f32 on gfx950)
__device__ __forceinline__ v2f fma2(v2f a, v2f b, v2f c) { return __builtin_elementwise_fma(a, b, c); }
__device__ __forceinline__ v2f max2(v2f a, v2f b) { return __builtin_elementwise_max(a, b); }

// DPP partial reductions (VALU pipe). ctrl must be an immediate.
template <int CTRL>
__device__ __forceinline__ float dpp_add(float v) {
    int t = __builtin_amdgcn_update_dpp(0, __float_as_int(v), CTRL, 0xf, 0xf, true);
    return v + __int_as_float(t);
}
__device__ __forceinline__ float swz_xor16_add(float v) {
    int t = __builtin_amdgcn_ds_swizzle(__float_as_int(v), 0x401F);
    return v + __int_as_float(t);
}
// after RED4+xor16: each 32-group holds its sum; total = group0 + group1 (uniform)
__device__ __forceinline__ float total64(float v) {
    return __int_as_float(__builtin_amdgcn_readlane(__float_as_int(v), 0))
         + __int_as_float(__builtin_amdgcn_readlane(__float_as_int(v), 32));
}
#define RED4_STAGES(q)  do {                                                    \
    _Pragma("unroll") for (int j = 0; j < 4; ++j) q[j] = dpp_add<0xB1>(q[j]);  \
    _Pragma("unroll") for (int j = 0; j < 4; ++j) q[j] = dpp_add<0x4E>(q[j]);  \
    _Pragma("unroll") for (int j = 0; j < 4; ++j) q[j] = dpp_add<0x141>(q[j]); \
    _Pragma("unroll") for (int j = 0; j < 4; ++j) q[j] = dpp_add<0x140>(q[j]); \
} while (0)

// ---------------- utility ----------------
__global__ void zero_u32_kernel(u32* __restrict__ p, int n) {
    int i = blockIdx.x * 256 + threadIdx.x;
    if (i < n) p[i] = 0u;
}

// ---------------- mega prep: count_edges + wpack(WT1) + wpack(WT2) ----------------
__global__ __launch_bounds__(256) void mega_prep_kernel(
    const int* __restrict__ ei, u32* __restrict__ counts,
    const float* __restrict__ w1a, const float* __restrict__ w1b, const float* __restrict__ w1c,
    u32* __restrict__ WT1,
    const float* __restrict__ w2a, const float* __restrict__ w2b, const float* __restrict__ w2c,
    u32* __restrict__ WT2)
{
    int b = blockIdx.x;
    int t = threadIdx.x;
    if (b < 3125) {
        int e = b * 256 + t;
        if (e < NE) atomicAdd(&counts[ei[NE + e]], 1u);
    } else if (b < 3125 + 96) {
        int i = (b - 3125) * 256 + t;           // 0 .. 3*128*64-1
        const int per = 128 * 64;
        int mat = i / per;
        int r = i - mat * per;
        const float* W = (mat == 0) ? w1a : (mat == 1) ? w1b : w1c;
        int col = r >> 6, c = r & 63;
        WT1[i] = bfpack2(W[(size_t)(2 * c) * 128 + col], W[(size_t)(2 * c + 1) * 128 + col]);
    } else {
        int i = (b - 3221) * 256 + t;           // 0 .. 3*64*64-1
        const int per = 64 * 64;
        int mat = i / per;
        int r = i - mat * per;
        const float* W = (mat == 0) ? w2a : (mat == 1) ? w2b : w2c;
        int col = r >> 6, c = r & 63;
        WT2[i] = bfpack2(W[(size_t)(2 * c) * 64 + col], W[(size_t)(2 * c + 1) * 64 + col]);
    }
}

// ---------------- scan part1 (blocks 0-48) + GEMM1 (blocks 49+) ----------------
__global__ __launch_bounds__(256) void scan1_gemm1_kernel(
    const u32* __restrict__ counts, u32* __restrict__ bsums,
    const float* __restrict__ X, const u32* __restrict__ Wt,
    u16* __restrict__ out0, float* __restrict__ out1, float* __restrict__ out2,
    const float* __restrict__ b0, const float* __restrict__ b1, const float* __restrict__ b2,
    int n)
{
    __shared__ __align__(16) u32 SMEM[64 * 68 * 2];
    int t = threadIdx.x;
    if (blockIdx.x < 49) {
        u32* ls = SMEM;
        int base = blockIdx.x * 1024 + t * 4;
        u32 s = 0;
#pragma unroll
        for (int j = 0; j < 4; ++j) { int idx = base + j; if (idx < NN) s += counts[idx]; }
        ls[t] = s;
        __syncthreads();
        for (int off = 128; off > 0; off >>= 1) {
            if (t < off) ls[t] += ls[t + off];
            __syncthreads();
        }
        if (t == 0) bsums[blockIdx.x] = ls[0];
        return;
    }
    u32* Xs = SMEM;
    u32* Ws = SMEM + 64 * 68;
    int row0 = (blockIdx.x - 49) * 64;
#pragma unroll
    for (int i = 0; i < 16; ++i) {
        int flat = t + 256 * i;
        int r = flat >> 6, c = flat & 63;
        int gr = row0 + r;
        u32 v = 0u;
        if (gr < n) {
            float2 f = *(const float2*)(X + (size_t)gr * 128 + c * 2);
            v = bfpack2(f.x, f.y);
        }
        Xs[r * 68 + c] = v;
    }
    int w = t >> 6, lane = t & 63;
    int l15 = lane & 15, quad = lane >> 4;
    for (int nb = 0; nb < 6; ++nb) {
#pragma unroll
        for (int i = 0; i < 16; ++i) {
            int flat = t + 256 * i;
            int cc = flat >> 6, c = flat & 63;
            Ws[cc * 68 + c] = Wt[(size_t)(nb * 64 + cc) * 64 + c];
        }
        __syncthreads();
        f32x4 acc[4] = {};
#pragma unroll
        for (int kk = 0; kk < 4; ++kk) {
            bf16x8 af = *(const bf16x8*)&Xs[(w * 16 + l15) * 68 + kk * 16 + quad * 4];
#pragma unroll
            for (int j = 0; j < 4; ++j) {
                bf16x8 bf = *(const bf16x8*)&Ws[(j * 16 + l15) * 68 + kk * 16 + quad * 4];
                acc[j] = __builtin_amdgcn_mfma_f32_16x16x32_bf16(af, bf, acc[j], 0, 0, 0);
            }
        }
        int mat = nb >> 1;
        int col0 = (nb & 1) * 64;
        const float* bp = (mat == 0) ? b0 : (mat == 1) ? b1 : b2;
#pragma unroll
        for (int j = 0; j < 4; ++j) {
            int col = col0 + j * 16 + l15;
            float bb = bp[col];
#pragma unroll
            for (int r = 0; r < 4; ++r) {
                int grow = row0 + w * 16 + quad * 4 + r;
                if (grow < n) {
                    float v = acc[j][r] + bb;
                    if (mat == 0) out0[(size_t)grow * 128 + col] = bf16of(v);
                    else if (mat == 1) out1[(size_t)grow * 128 + col] = v;
                    else out2[(size_t)grow * 128 + col] = v;
                }
            }
        }
        __syncthreads();
    }
}

// ---------------- scan final (block-sum scan inlined as a wave scan) ----------------
__global__ __launch_bounds__(256) void scan_final_kernel(
    const u32* __restrict__ counts, const u32* __restrict__ bsums, int* __restrict__ rowptr)
{
    __shared__ u32 ls[256];
    __shared__ u32 prefsh;
    int t = threadIdx.x;
    if (t < 64) {
        u32 v = (t < 49) ? bsums[t] : 0u;
#pragma unroll
        for (int off = 1; off < 64; off <<= 1) {
            u32 tv = __shfl_up(v, off, 64);
            if (t >= off) v += tv;
        }
        u32 ex = __shfl_up(v, 1, 64);
        if (t == 0) ex = 0u;
        if (t == (int)blockIdx.x) prefsh = ex;
    }
    __syncthreads();
    u32 bpref = prefsh;
    int base = blockIdx.x * 1024 + t * 4;
    u32 c[4];
    u32 s = 0;
#pragma unroll
    for (int j = 0; j < 4; ++j) { int idx = base + j; c[j] = (idx < NN) ? counts[idx] : 0u; s += c[j]; }
    ls[t] = s;
    __syncthreads();
    for (int off = 1; off < 256; off <<= 1) {
        u32 add = (t >= off) ? ls[t - off] : 0u;
        __syncthreads();
        ls[t] += add;
        __syncthreads();
    }
    u32 run = ls[t] - s + bpref;
#pragma unroll
    for (int j = 0; j < 4; ++j) { int idx = base + j; if (idx < NN) { rowptr[idx] = (int)run; } run += c[j]; }
    if (blockIdx.x == 0 && t == 0) rowptr[NN] = NE;
}

// ---------------- scatter: CSR-order srcs + CSR-order packed edge attrs ----------------
__global__ __launch_bounds__(256) void scatter_pack_kernel(
    const int* __restrict__ ei, const float* __restrict__ ea, const int* __restrict__ rowptr,
    u32* __restrict__ cursors, int* __restrict__ srcs, u32* __restrict__ eahs)
{
    int e = blockIdx.x * 256 + threadIdx.x;
    if (e < NE) {
        int sn = ei[e];
        int d = ei[NE + e];
        u32 pos = atomicAdd(&cursors[d], 1u);
        int slot = rowptr[d] + (int)pos;
        srcs[slot] = sn;
        const float4* s4 = (const float4*)(ea + (size_t)e * 16);
        float4 f0 = s4[0], f1 = s4[1], f2 = s4[2], f3 = s4[3];
        uint4 o0 = {bfpack2(f0.x, f0.y), bfpack2(f0.z, f0.w), bfpack2(f1.x, f1.y), bfpack2(f1.z, f1.w)};
        uint4 o1 = {bfpack2(f2.x, f2.y), bfpack2(f2.z, f2.w), bfpack2(f3.x, f3.y), bfpack2(f3.z, f3.w)};
        *(uint4*)(eahs + (size_t)slot * 8) = o0;
        *(uint4*)(eahs + (size_t)slot * 8 + 4) = o1;
    }
}

// ---------------- fused GATv2 layer 1 (H=2, C=64) ----------------
// Persistent chunked waves: grid = 2048 blocks (8/CU, full residency); each wave
// owns a CONTIGUOUS node range [w*NN/NW, (w+1)*NN/NW) -> per-wave work ~Poisson(104)
// (sigma ~10%) instead of 1 node/wave (sigma 25% + block-retire quantization, which
// capped occupancy at 51%). Edge stream stays sequential per wave.
#define GAT_BLOCKS 2048
#define GAT_NW (GAT_BLOCKS * 4)
__global__ __launch_bounds__(256) void gat1_fused_kernel(
    const u32* __restrict__ xlp, const float* __restrict__ xr,
    const u32* __restrict__ eahs, const int* __restrict__ srcs,
    const int* __restrict__ rowptr, const float* __restrict__ We,
    const float* __restrict__ att, const float* __restrict__ bias,
    float* __restrict__ out)
{
    int lane = threadIdx.x & 63;
    int wave = (blockIdx.x * 256 + threadIdx.x) >> 6;
    int c0 = lane * 2;
    v2f w[16];
#pragma unroll
    for (int k = 0; k < 16; ++k) {
        float2 t2 = *(const float2*)(We + k * 128 + c0);
        w[k] = (v2f){t2.x, t2.y};
    }
    float at0 = att[c0], at1 = att[c0 + 1];
    float2 bt = *(const float2*)(bias + c0);

    int d0 = (int)(((long long)wave * NN) / GAT_NW);
    int d1 = (int)(((long long)(wave + 1) * NN) / GAT_NW);

    for (int d = d0; d < d1; ++d) {
        int du = __builtin_amdgcn_readfirstlane(d);
        int beg = rowptr[du], end = rowptr[du + 1];
        float2 xq = *(const float2*)(xr + (size_t)du * 128 + c0);
        v2f xrv = {xq.x, xq.y};
        float s = 0.f;
        v2f acc = {0.f, 0.f};

        int cnt = (end - beg) >> 2;
        int sA[4]; uint4 eA0[4], eA1[4]; u32 xA[4];
        int sB[4]; uint4 eB0[4], eB1[4]; u32 xB[4];

#define G1_LOAD(SN, E0, E1, X, base_) do {                                     \
    _Pragma("unroll")                                                          \
    for (int j = 0; j < 4; ++j) SN[j] = srcs[(base_) + j];                     \
    _Pragma("unroll")                                                          \
    for (int j = 0; j < 4; ++j) {                                              \
        const uint4* e4_ = (const uint4*)(eahs + (size_t)((base_) + j) * 8);   \
        E0[j] = e4_[0]; E1[j] = e4_[1];                                        \
    }                                                                          \
    _Pragma("unroll")                                                          \
    for (int j = 0; j < 4; ++j) X[j] = xlp[(size_t)SN[j] * 64 + lane];         \
    __builtin_amdgcn_sched_barrier(0);                                         \
} while (0)

#define G1_PROC(E0, E1, X) do {                                                \
    float q[4]; v2f xv[4];                                                     \
    _Pragma("unroll")                                                          \
    for (int j = 0; j < 4; ++j) {                                              \
        u32 ew[8] = {E0[j].x, E0[j].y, E0[j].z, E0[j].w,                       \
                     E1[j].x, E1[j].y, E1[j].z, E1[j].w};                      \
        v2f e = {0.f, 0.f};                                                    \
        _Pragma("unroll")                                                      \
        for (int kk = 0; kk < 8; ++kk) {                                       \
            u32 pk = ew[kk];                                                   \
            float s1 = uaf(pk << 16), s2 = uaf(pk & 0xffff0000u);              \
            e = fma2(w[2 * kk],     (v2f){s1, s1}, e);                         \
            e = fma2(w[2 * kk + 1], (v2f){s2, s2}, e);                         \
        }                                                                      \
        u32 pxv = X[j];                                                        \
        xv[j] = (v2f){uaf(pxv << 16), uaf(pxv & 0xffff0000u)};                 \
        v2f mm = xv[j] + xrv + e;                                              \
        v2f lk = max2(mm, mm * 0.2f);                                          \
        q[j] = fmaf(lk.x, at0, lk.y * at1);                                    \
    }                                                                          \
    RED4_STAGES(q);                                                            \
    _Pragma("unroll")                                                          \
    for (int j = 0; j < 4; ++j) q[j] = swz_xor16_add(q[j]);                    \
    float w0 = __expf(q[0]), w1 = __expf(q[1]);                                \
    float w2 = __expf(q[2]), w3 = __expf(q[3]);                                \
    s += (w0 + w1) + (w2 + w3);                                                \
    acc = fma2(xv[0], (v2f){w0, w0}, acc);                                     \
    acc = fma2(xv[1], (v2f){w1, w1}, acc);                                     \
    acc = fma2(xv[2], (v2f){w2, w2}, acc);                                     \
    acc = fma2(xv[3], (v2f){w3, w3}, acc);                                     \
} while (0)

        if (cnt > 0) {
            G1_LOAD(sA, eA0, eA1, xA, beg);
            int g = 0;
            for (; g + 2 <= cnt; g += 2) {
                G1_LOAD(sB, eB0, eB1, xB, beg + (g + 1) * 4);
                G1_PROC(eA0, eA1, xA);
                if (g + 2 < cnt) G1_LOAD(sA, eA0, eA1, xA, beg + (g + 2) * 4);
                G1_PROC(eB0, eB1, xB);
            }
            if (g < cnt) G1_PROC(eA0, eA1, xA);
        }
#undef G1_LOAD
#undef G1_PROC
        for (int i = beg + cnt * 4; i < end; ++i) {
            const uint4* e4 = (const uint4*)(eahs + (size_t)i * 8);
            uint4 ql = e4[0], qh = e4[1];
            u32 er[8] = {ql.x, ql.y, ql.z, ql.w, qh.x, qh.y, qh.z, qh.w};
            int sn = srcs[i];
            u32 px = xlp[(size_t)sn * 64 + lane];
            v2f e = {0.f, 0.f};
#pragma unroll
            for (int kk = 0; kk < 8; ++kk) {
                u32 pk = er[kk];
                float s1 = uaf(pk << 16), s2 = uaf(pk & 0xffff0000u);
                e = fma2(w[2 * kk],     (v2f){s1, s1}, e);
                e = fma2(w[2 * kk + 1], (v2f){s2, s2}, e);
            }
            v2f xv = {uaf(px << 16), uaf(px & 0xffff0000u)};
            v2f mm = xv + xrv + e;
            v2f lk = max2(mm, mm * 0.2f);
            float p = fmaf(lk.x, at0, lk.y * at1);
            p = dpp_add<0xB1>(p);
            p = dpp_add<0x4E>(p);
            p = dpp_add<0x141>(p);
            p = dpp_add<0x140>(p);
            p = swz_xor16_add(p);
            float ww = __expf(p);
            s += ww;
            acc = fma2(xv, (v2f){ww, ww}, acc);
        }
        float inv = 1.f / (s + 1e-16f);
        float2 o;
        o.x = fmaf(acc.x, inv, bt.x);
        o.y = fmaf(acc.y, inv, bt.y);
        *(float2*)(out + (size_t)d * 128 + c0) = o;
    }
}

// ---------------- fused GATv2 layer 2 (H=1, C=64) ----------------
__global__ __launch_bounds__(256) void gat2_fused_kernel(
    const u16* __restrict__ xlp, const float* __restrict__ xr,
    const u32* __restrict__ eahs, const int* __restrict__ srcs,
    const int* __restrict__ rowptr, const float* __restrict__ We,
    const float* __restrict__ att, const float* __restrict__ bias,
    float* __restrict__ out)
{
    int lane = threadIdx.x & 63;
    int wave = (blockIdx.x * 256 + threadIdx.x) >> 6;
    float w[16];
#pragma unroll
    for (int k = 0; k < 16; ++k) w[k] = We[k * 64 + lane];
    float at0 = att[lane];
    float bb = bias[lane];

    int d0 = (int)(((long long)wave * NN) / GAT_NW);
    int d1 = (int)(((long long)(wave + 1) * NN) / GAT_NW);

    for (int d = d0; d < d1; ++d) {
        int du = __builtin_amdgcn_readfirstlane(d);
        int beg = rowptr[du], end = rowptr[du + 1];
        float xrv = xr[(size_t)du * 64 + lane];
        float s = 0.f, acc = 0.f;

        int cnt = (end - beg) >> 2;
        int sA[4]; uint4 eA0[4], eA1[4]; float xA[4];
        int sB[4]; uint4 eB0[4], eB1[4]; float xB[4];

#define G2_LOAD(SN, E0, E1, X, base_) do {                                     \
    _Pragma("unroll")                                                          \
    for (int j = 0; j < 4; ++j) SN[j] = srcs[(base_) + j];                     \
    _Pragma("unroll")                                                          \
    for (int j = 0; j < 4; ++j) {                                              \
        const uint4* e4_ = (const uint4*)(eahs + (size_t)((base_) + j) * 8);   \
        E0[j] = e4_[0]; E1[j] = e4_[1];                                        \
    }                                                                          \
    _Pragma("unroll")                                                          \
    for (int j = 0; j < 4; ++j)                                                \
        X[j] = uaf((u32)xlp[(size_t)SN[j] * 64 + lane] << 16);                 \
    __builtin_amdgcn_sched_barrier(0);                                         \
} while (0)

#define G2_PROC(E0, E1, X) do {                                                \
    float q[4];                                                                \
    _Pragma("unroll")                                                          \
    for (int j = 0; j < 4; ++j) {                                              \
        u32 ew[8] = {E0[j].x, E0[j].y, E0[j].z, E0[j].w,                       \
                     E1[j].x, E1[j].y, E1[j].z, E1[j].w};                      \
        float e = 0.f;                                                         \
        _Pragma("unroll")                                                      \
        for (int kk = 0; kk < 8; ++kk) {                                       \
            u32 pk = ew[kk];                                                   \
            float s1 = uaf(pk << 16), s2 = uaf(pk & 0xffff0000u);              \
            e = fmaf(s1, w[2 * kk], e);                                        \
            e = fmaf(s2, w[2 * kk + 1], e);                                    \
        }                                                                      \
        float mm = X[j] + xrv + e;                                             \
        mm = fmaxf(mm, 0.2f * mm);                                             \
        q[j] = mm * at0;                                                       \
    }                                                                          \
    RED4_STAGES(q);                                                            \
    _Pragma("unroll")                                                          \
    for (int j = 0; j < 4; ++j) { q[j] = swz_xor16_add(q[j]); q[j] = total64(q[j]); } \
    float w0 = __expf(q[0]), w1 = __expf(q[1]);                                \
    float w2 = __expf(q[2]), w3 = __expf(q[3]);                                \
    s += (w0 + w1) + (w2 + w3);                                                \
    acc += fmaf(w0, X[0], fmaf(w1, X[1], fmaf(w2, X[2], w3 * X[3])));          \
} while (0)

        if (cnt > 0) {
            G2_LOAD(sA, eA0, eA1, xA, beg);
            int g = 0;
            for (; g + 2 <= cnt; g += 2) {
                G2_LOAD(sB, eB0, eB1, xB, beg + (g + 1) * 4);
                G2_PROC(eA0, eA1, xA);
                if (g + 2 < cnt) G2_LOAD(sA, eA0, eA1, xA, beg + (g + 2) * 4);
                G2_PROC(eB0, eB1, xB);
            }
            if (g < cnt) G2_PROC(eA0, eA1, xA);
        }
#undef G2_LOAD
#undef G2_PROC
        for (int i = beg + cnt * 4; i < end; ++i) {
            const uint4* e4 = (const uint4*)(eahs + (size_t)i * 8);
            uint4 ql = e4[0], qh = e4[1];
            u32 er[8] = {ql.x, ql.y, ql.z, ql.w, qh.x, qh.y, qh.z, qh.w};
            int sn = srcs[i];
            float xv = uaf((u32)xlp[(size_t)sn * 64 + lane] << 16);
            float e = 0.f;
#pragma unroll
            for (int kk = 0; kk < 8; ++kk) {
                u32 pk = er[kk];
                float s1 = uaf(pk << 16), s2 = uaf(pk & 0xffff0000u);
                e = fmaf(s1, w[2 * kk], e);
                e = fmaf(s2, w[2 * kk + 1], e);
            }
            float mm = xv + xrv + e;
            mm = fmaxf(mm, 0.2f * mm);
            float p = mm * at0;
            p = dpp_add<0xB1>(p);
            p = dpp_add<0x4E>(p);
            p = dpp_add<0x141>(p);
            p = dpp_add<0x140>(p);
            p = swz_xor16_add(p);
            p = total64(p);
            float ww = __expf(p);
            s += ww;
            acc = fmaf(ww, xv, acc);
        }
        out[(size_t)d * 64 + lane] = acc / (s + 1e-16f) + bb;
    }
}

// ---------------- fused MFMA GEMM, layer 2 (BN1+skip+ELU+pack in staging) ----------------
__global__ __launch_bounds__(256) void gemm2_fused_kernel(
    const float* __restrict__ H, const float* __restrict__ XPin,
    const float* __restrict__ stats, const float* __restrict__ bg, const float* __restrict__ bbv,
    const u32* __restrict__ Wt,
    u16* __restrict__ out0, float* __restrict__ out1, float* __restrict__ out2,
    const float* __restrict__ b0, const float* __restrict__ b1, const float* __restrict__ b2,
    int n)
{
    __shared__ __align__(16) u32 Xs[64 * 68];
    __shared__ __align__(16) u32 Ws[64 * 68];
    int t = threadIdx.x;
    int row0 = blockIdx.x * 64;
    int c = t & 63;
    int ch0 = 2 * c, ch1 = ch0 + 1;
    float mu0 = stats[ch0] * (1.f / NN), mu1 = stats[ch1] * (1.f / NN);
    float var0 = stats[128 + ch0] * (1.f / NN) - mu0 * mu0;
    float var1 = stats[128 + ch1] * (1.f / NN) - mu1 * mu1;
    float s0 = rsqrtf(var0 + 1e-5f) * bg[ch0];
    float s1 = rsqrtf(var1 + 1e-5f) * bg[ch1];
    float t0 = bbv[ch0] - mu0 * s0;
    float t1 = bbv[ch1] - mu1 * s1;
#pragma unroll
    for (int i = 0; i < 16; ++i) {
        int flat = t + 256 * i;
        int r = flat >> 6;
        int gr = row0 + r;
        u32 v = 0u;
        if (gr < n) {
            float2 hv = *(const float2*)(H + (size_t)gr * 128 + ch0);
            float2 xv = *(const float2*)(XPin + (size_t)gr * 128 + ch0);
            float v0 = fmaf(hv.x, s0, t0) + xv.x;
            float v1 = fmaf(hv.y, s1, t1) + xv.y;
            v0 = (v0 > 0.f) ? v0 : expm1f(v0);
            v1 = (v1 > 0.f) ? v1 : expm1f(v1);
            v = bfpack2(v0, v1);
        }
        Xs[r * 68 + c] = v;
    }
    int w = t >> 6, lane = t & 63;
    int l15 = lane & 15, quad = lane >> 4;
    for (int nb = 0; nb < 3; ++nb) {
#pragma unroll
        for (int i = 0; i < 16; ++i) {
            int flat = t + 256 * i;
            int cc = flat >> 6, cw = flat & 63;
            Ws[cc * 68 + cw] = Wt[(size_t)(nb * 64 + cc) * 64 + cw];
        }
        __syncthreads();
        f32x4 acc[4] = {};
#pragma unroll
        for (int kk = 0; kk < 4; ++kk) {
            bf16x8 af = *(const bf16x8*)&Xs[(w * 16 + l15) * 68 + kk * 16 + quad * 4];
#pragma unroll
            for (int j = 0; j < 4; ++j) {
                bf16x8 bf = *(const bf16x8*)&Ws[(j * 16 + l15) * 68 + kk * 16 + quad * 4];
                acc[j] = __builtin_amdgcn_mfma_f32_16x16x32_bf16(af, bf, acc[j], 0, 0, 0);
            }
        }
        const float* bp = (nb == 0) ? b0 : (nb == 1) ? b1 : b2;
#pragma unroll
        for (int j = 0; j < 4; ++j) {
            int col = j * 16 + l15;
            float bb = bp[col];
#pragma unroll
            for (int r = 0; r < 4; ++r) {
                int grow = row0 + w * 16 + quad * 4 + r;
                if (grow < n) {
                    float v = acc[j][r] + bb;
                    if (nb == 0) out0[(size_t)grow * 64 + col] = bf16of(v);
                    else if (nb == 1) out1[(size_t)grow * 64 + col] = v;
                    else out2[(size_t)grow * 64 + col] = v;
                }
            }
        }
        __syncthreads();
    }
}

// ---------------- batch-norm stats (391 blocks: full CU coverage) ----------------
template <int C>
__global__ __launch_bounds__(256) void bn_stats_kernel(const float* __restrict__ h, float* __restrict__ stats) {
    const int SUB = 256 / C;
    int t = threadIdx.x;
    int c = t & (C - 1);
    int rs = t / C;
    int r0 = blockIdx.x * 128;
    int r1 = min(NN, r0 + 128);
    float s = 0.f, s2 = 0.f;
    for (int r = r0 + rs; r < r1; r += SUB) {
        float v = h[(size_t)r * C + c];
        s += v; s2 = fmaf(v, v, s2);
    }
    __shared__ float ls[256], ls2[256];
    ls[t] = s; ls2[t] = s2;
    __syncthreads();
    if (rs == 0) {
        for (int j = 1; j < SUB; ++j) { s += ls[j * C + c]; s2 += ls2[j * C + c]; }
        atomicAdd(&stats[c], s);
        atomicAdd(&stats[C + c], s2);
    }
}

// ---------------- pool accumulate: BN2+skip+ELU fused, per-graph atomic sum/max ----------------
__global__ __launch_bounds__(256) void pool_acc_kernel(
    const float* __restrict__ D, const float* __restrict__ xp2,
    const float* __restrict__ stats, const float* __restrict__ bg, const float* __restrict__ bbv,
    const int* __restrict__ batch,
    float* __restrict__ psum, u32* __restrict__ pmax)
{
    int t = threadIdx.x;
    int lane = t & 63, rs = t >> 6;
    float mu = stats[lane] * (1.f / NN);
    float var = stats[64 + lane] * (1.f / NN) - mu * mu;
    float sc = rsqrtf(var + 1e-5f) * bg[lane];
    float tb = bbv[lane] - mu * sc;
    int r0 = blockIdx.x * 128;
    int r1 = min(NN, r0 + 128);
    int curg = -1;
    float sum = 0.f, mx = -INFINITY;
    for (int r = r0 + rs; r < r1; r += 4) {
        int g = batch[r];               // wave-uniform (lane indexes channel only)
        if (g != curg) {
            if (curg >= 0) {
                atomicAdd(&psum[curg * 64 + lane], sum);
                atomicMax(&pmax[curg * 64 + lane], fenc(mx));
            }
            curg = g; sum = 0.f; mx = -INFINITY;
        }
        float v = fmaf(D[(size_t)r * 64 + lane], sc, tb) + xp2[(size_t)r * 64 + lane];
        v = (v > 0.f) ? v : expm1f(v);
        sum += v; mx = fmaxf(mx, v);
    }
    if (curg >= 0) {
        atomicAdd(&psum[curg * 64 + lane], sum);
        atomicMax(&pmax[curg * 64 + lane], fenc(mx));
    }
}

// ---------------- pool finalize + classifier (tiny) ----------------
__global__ __launch_bounds__(64) void pool_fin_kernel(
    const float* __restrict__ psum, const u32* __restrict__ pmax,
    const int* __restrict__ batch,
    const float* __restrict__ cw, const float* __restrict__ cb,
    float* __restrict__ outp)
{
    int g = blockIdx.x;
    int lane = threadIdx.x;
    int lo = 0, hi = NN;
    while (lo < hi) { int mid = (lo + hi) >> 1; if (batch[mid] < g) lo = mid + 1; else hi = mid; }
    int s0 = lo;
    hi = NN;
    while (lo < hi) { int mid = (lo + hi) >> 1; if (batch[mid] < g + 1) lo = mid + 1; else hi = mid; }
    int e0 = lo;
    float cnt = (float)(e0 - s0);
    float mean = psum[g * 64 + lane] / fmaxf(cnt, 1.f);
    float mx = fdec(pmax[g * 64 + lane]);
#pragma unroll
    for (int c = 0; c < 2; ++c) {
        float v = fmaf(mean, cw[lane * 2 + c], mx * cw[(64 + lane) * 2 + c]);
        v = dpp_add<0xB1>(v);
        v = dpp_add<0x4E>(v);
        v = dpp_add<0x141>(v);
        v = dpp_add<0x140>(v);
        v = swz_xor16_add(v);
        v = total64(v);
        if (lane == 0) outp[g * 2 + c] = v + cb[c];
    }
}

extern "C" void kernel_launch(void* const* d_in, const int* in_sizes, int n_in,
                              void* d_out, int out_size, void* d_ws, size_t ws_size,
                              hipStream_t stream)
{
    const float* x       = (const float*)d_in[0];
    const int*   ei      = (const int*)d_in[1];
    const float* ea      = (const float*)d_in[2];
    const int*   batch   = (const int*)d_in[3];
    const float* skip1_w = (const float*)d_in[4];
    const float* skip1_b = (const float*)d_in[5];
    const float* c1_wl   = (const float*)d_in[6];
    const float* c1_bl   = (const float*)d_in[7];
    const float* c1_wr   = (const float*)d_in[8];
    const float* c1_br   = (const float*)d_in[9];
    const float* c1_we   = (const float*)d_in[10];
    const float* c1_att  = (const float*)d_in[11];
    const float* c1_bias = (const float*)d_in[12];
    const float* bn1_g   = (const float*)d_in[13];
    const float* bn1_b   = (const float*)d_in[14];
    const float* skip2_w = (const float*)d_in[15];
    const float* skip2_b = (const float*)d_in[16];
    const float* c2_wl   = (const float*)d_in[17];
    const float* c2_bl   = (const float*)d_in[18];
    const float* c2_wr   = (const float*)d_in[19];
    const float* c2_br   = (const float*)d_in[20];
    const float* c2_we   = (const float*)d_in[21];
    const float* c2_att  = (const float*)d_in[22];
    const float* c2_bias = (const float*)d_in[23];
    const float* bn2_g   = (const float*)d_in[24];
    const float* bn2_b   = (const float*)d_in[25];
    const float* cls_w   = (const float*)d_in[26];
    const float* cls_b   = (const float*)d_in[27];
    float* outp = (float*)d_out;

    float* ws = (float*)d_ws;
    size_t o = 0;
    float* A   = ws + o; o += 6400000;   // XL1P bf16 [n][128]; layer2: XL2P bf16 (lower) + xr2 fp32 (upper)
    float* B   = ws + o; o += 6400000;   // xr1 fp32 [n][128]
    float* Cb  = ws + o; o += 6400000;   // xp1 fp32 [n][128]
    float* D   = ws + o; o += 6400000;   // h1 pre-BN [n][128] ; later h2 pre-BN [n][64]
    int*   SRCS  = (int*)(ws + o); o += 800000;    // CSR-ordered src nodes
    u32*   EAHS  = (u32*)(ws + o); o += 6400000;   // CSR-ordered ea packed bf16 [E][8]
    u32*   XPx   = (u32*)(ws + o); o += 3200000;   // xp2 fp32 [n][64]
    u32*   WT1   = (u32*)(ws + o); o += 24576;     // [384][64]
    u32*   WT2   = (u32*)(ws + o); o += 12288;     // [192][64]
    // ---- contiguous zeroed region: COUNTS..PMAX (106784 u32) ----
    u32*   COUNTS  = (u32*)(ws + o); o += 50000;
    u32*   CURSORS = (u32*)(ws + o); o += 50000;
    float* STATS1  = ws + o; o += 256;
    float* STATS2  = ws + o; o += 128;
    float* PSUM    = ws + o; o += 3200;            // [G][64] pooled sum
    u32*   PMAX    = (u32*)(ws + o); o += 3200;    // [G][64] pooled max (monotonic enc)
    // ---- end zeroed region ----
    int*   ROWPTR  = (int*)(ws + o); o += 50016;
    u32*   BSUMS   = (u32*)(ws + o); o += 64;

    u16*   XL1P = (u16*)A;               // [n][128] bf16
    u16*   XL2P = (u16*)A;               // [n][64] bf16 (layer 2)
    float* xr2  = A + 3200000;
    float* xp2  = (float*)XPx;           // [n][64] fp32

    // zero COUNTS + CURSORS + STATS1 + STATS2 + PSUM + PMAX (contiguous, 106784 u32)
    zero_u32_kernel<<<(106784 + 255) / 256, 256, 0, stream>>>(COUNTS, 106784);
    // count_edges + wpack(WT1) + wpack(WT2) in one launch
    mega_prep_kernel<<<3269, 256, 0, stream>>>(ei, COUNTS,
        c1_wl, c1_wr, skip1_w, WT1, c2_wl, c2_wr, skip2_w, WT2);
    // scan part1 (49 blocks) runs concurrently with GEMM1 (782 blocks)
    scan1_gemm1_kernel<<<831, 256, 0, stream>>>(COUNTS, BSUMS, x, WT1,
        XL1P, B, Cb, c1_bl, c1_br, skip1_b, NN);
    scan_final_kernel<<<49, 256, 0, stream>>>(COUNTS, BSUMS, ROWPTR);
    scatter_pack_kernel<<<3125, 256, 0, stream>>>(ei, ea, ROWPTR, CURSORS, SRCS, EAHS);

    // ---- layer 1 ----
    gat1_fused_kernel<<<GAT_BLOCKS, 256, 0, stream>>>((const u32*)XL1P, B, EAHS, SRCS, ROWPTR,
        c1_we, c1_att, c1_bias, D);
    bn_stats_kernel<128><<<391, 256, 0, stream>>>(D, STATS1);

    // ---- layer 2 (BN1-apply + skip + ELU fused into the GEMM staging) ----
    gemm2_fused_kernel<<<782, 256, 0, stream>>>(D, Cb, STATS1, bn1_g, bn1_b, WT2,
        XL2P, xr2, xp2, c2_bl, c2_br, skip2_b, NN);
    gat2_fused_kernel<<<GAT_BLOCKS, 256, 0, stream>>>(XL2P, xr2, EAHS, SRCS, ROWPTR,
        c2_we, c2_att, c2_bias, D);
    bn_stats_kernel<64><<<391, 256, 0, stream>>>(D, STATS2);

    // ---- pool: wide atomic accumulate (BN2+skip+ELU fused) + tiny finalize/classify ----
    pool_acc_kernel<<<(NN + 127) / 128, 256, 0, stream>>>(D, xp2, STATS2, bn2_g, bn2_b,
        batch, PSUM, PMAX);
    pool_fin_kernel<<<GG, 64, 0, stream>>>(PSUM, PMAX, batch, cls_w, cls_b, outp);
}

// Round 22
// 487.499 us; speedup vs baseline: 1.2933x; 1.0613x over previous
//
#include <hip/hip_runtime.h>
#include <math.h>

#define NN 50000
#define NE 800000
#define GG 50

typedef unsigned int u32;
typedef unsigned short u16;
typedef float v2f __attribute__((ext_vector_type(2)));
typedef short bf16x8 __attribute__((ext_vector_type(8)));
typedef float f32x4 __attribute__((ext_vector_type(4)));

__device__ __forceinline__ float uaf(u32 x) { return __uint_as_float(x); }

__device__ __forceinline__ u32 bfpack2(float x, float y) {
    u32 a = __float_as_uint(x), b = __float_as_uint(y);
    a = (a + 0x7fffu + ((a >> 16) & 1u)) >> 16;
    b = (b + 0x7fffu + ((b >> 16) & 1u)) & 0xffff0000u;
    return b | a;
}
__device__ __forceinline__ u16 bf16of(float x) {
    u32 a = __float_as_uint(x);
    return (u16)((a + 0x7fffu + ((a >> 16) & 1u)) >> 16);
}

// monotonic float<->u32 encoding for atomicMax on floats
__device__ __forceinline__ u32 fenc(float x) {
    u32 u = __float_as_uint(x);
    return (u >> 31) ? ~u : (u | 0x80000000u);
}
__device__ __forceinline__ float fdec(u32 m) {
    return (m >> 31) ? uaf(m & 0x7fffffffu) : uaf(~m);
}

// packed fp32 math (v_pk_fma_f32 / v_pk_max_f32 on gfx950)
__device__ __forceinline__ v2f fma2(v2f a, v2f b, v2f c) { return __builtin_elementwise_fma(a, b, c); }
__device__ __forceinline__ v2f max2(v2f a, v2f b) { return __builtin_elementwise_max(a, b); }

// DPP partial reductions (VALU pipe). ctrl must be an immediate.
template <int CTRL>
__device__ __forceinline__ float dpp_add(float v) {
    int t = __builtin_amdgcn_update_dpp(0, __float_as_int(v), CTRL, 0xf, 0xf, true);
    return v + __int_as_float(t);
}
__device__ __forceinline__ float swz_xor16_add(float v) {
    int t = __builtin_amdgcn_ds_swizzle(__float_as_int(v), 0x401F);
    return v + __int_as_float(t);
}
// after RED4+xor16: each 32-group holds its sum; total = group0 + group1 (uniform)
__device__ __forceinline__ float total64(float v) {
    return __int_as_float(__builtin_amdgcn_readlane(__float_as_int(v), 0))
         + __int_as_float(__builtin_amdgcn_readlane(__float_as_int(v), 32));
}
#define RED4_STAGES(q)  do {                                                    \
    _Pragma("unroll") for (int j = 0; j < 4; ++j) q[j] = dpp_add<0xB1>(q[j]);  \
    _Pragma("unroll") for (int j = 0; j < 4; ++j) q[j] = dpp_add<0x4E>(q[j]);  \
    _Pragma("unroll") for (int j = 0; j < 4; ++j) q[j] = dpp_add<0x141>(q[j]); \
    _Pragma("unroll") for (int j = 0; j < 4; ++j) q[j] = dpp_add<0x140>(q[j]); \
} while (0)

// ---------------- utility ----------------
__global__ void zero_u32_kernel(u32* __restrict__ p, int n) {
    int i = blockIdx.x * 256 + threadIdx.x;
    if (i < n) p[i] = 0u;
}

// ---------------- mega prep: count_edges + wpack(WT1) + wpack(WT2) ----------------
__global__ __launch_bounds__(256) void mega_prep_kernel(
    const int* __restrict__ ei, u32* __restrict__ counts,
    const float* __restrict__ w1a, const float* __restrict__ w1b, const float* __restrict__ w1c,
    u32* __restrict__ WT1,
    const float* __restrict__ w2a, const float* __restrict__ w2b, const float* __restrict__ w2c,
    u32* __restrict__ WT2)
{
    int b = blockIdx.x;
    int t = threadIdx.x;
    if (b < 3125) {
        int e = b * 256 + t;
        if (e < NE) atomicAdd(&counts[ei[NE + e]], 1u);
    } else if (b < 3125 + 96) {
        int i = (b - 3125) * 256 + t;           // 0 .. 3*128*64-1
        const int per = 128 * 64;
        int mat = i / per;
        int r = i - mat * per;
        const float* W = (mat == 0) ? w1a : (mat == 1) ? w1b : w1c;
        int col = r >> 6, c = r & 63;
        WT1[i] = bfpack2(W[(size_t)(2 * c) * 128 + col], W[(size_t)(2 * c + 1) * 128 + col]);
    } else {
        int i = (b - 3221) * 256 + t;           // 0 .. 3*64*64-1
        const int per = 64 * 64;
        int mat = i / per;
        int r = i - mat * per;
        const float* W = (mat == 0) ? w2a : (mat == 1) ? w2b : w2c;
        int col = r >> 6, c = r & 63;
        WT2[i] = bfpack2(W[(size_t)(2 * c) * 64 + col], W[(size_t)(2 * c + 1) * 64 + col]);
    }
}

// ---------------- scan part1 (blocks 0-48) + GEMM1 (blocks 49+) ----------------
__global__ __launch_bounds__(256) void scan1_gemm1_kernel(
    const u32* __restrict__ counts, u32* __restrict__ bsums,
    const float* __restrict__ X, const u32* __restrict__ Wt,
    u16* __restrict__ out0, float* __restrict__ out1, float* __restrict__ out2,
    const float* __restrict__ b0, const float* __restrict__ b1, const float* __restrict__ b2,
    int n)
{
    __shared__ __align__(16) u32 SMEM[64 * 68 * 2];
    int t = threadIdx.x;
    if (blockIdx.x < 49) {
        u32* ls = SMEM;
        int base = blockIdx.x * 1024 + t * 4;
        u32 s = 0;
#pragma unroll
        for (int j = 0; j < 4; ++j) { int idx = base + j; if (idx < NN) s += counts[idx]; }
        ls[t] = s;
        __syncthreads();
        for (int off = 128; off > 0; off >>= 1) {
            if (t < off) ls[t] += ls[t + off];
            __syncthreads();
        }
        if (t == 0) bsums[blockIdx.x] = ls[0];
        return;
    }
    u32* Xs = SMEM;
    u32* Ws = SMEM + 64 * 68;
    int row0 = (blockIdx.x - 49) * 64;
#pragma unroll
    for (int i = 0; i < 16; ++i) {
        int flat = t + 256 * i;
        int r = flat >> 6, c = flat & 63;
        int gr = row0 + r;
        u32 v = 0u;
        if (gr < n) {
            float2 f = *(const float2*)(X + (size_t)gr * 128 + c * 2);
            v = bfpack2(f.x, f.y);
        }
        Xs[r * 68 + c] = v;
    }
    int w = t >> 6, lane = t & 63;
    int l15 = lane & 15, quad = lane >> 4;
    for (int nb = 0; nb < 6; ++nb) {
#pragma unroll
        for (int i = 0; i < 16; ++i) {
            int flat = t + 256 * i;
            int cc = flat >> 6, c = flat & 63;
            Ws[cc * 68 + c] = Wt[(size_t)(nb * 64 + cc) * 64 + c];
        }
        __syncthreads();
        f32x4 acc[4] = {};
#pragma unroll
        for (int kk = 0; kk < 4; ++kk) {
            bf16x8 af = *(const bf16x8*)&Xs[(w * 16 + l15) * 68 + kk * 16 + quad * 4];
#pragma unroll
            for (int j = 0; j < 4; ++j) {
                bf16x8 bf = *(const bf16x8*)&Ws[(j * 16 + l15) * 68 + kk * 16 + quad * 4];
                acc[j] = __builtin_amdgcn_mfma_f32_16x16x32_bf16(af, bf, acc[j], 0, 0, 0);
            }
        }
        int mat = nb >> 1;
        int col0 = (nb & 1) * 64;
        const float* bp = (mat == 0) ? b0 : (mat == 1) ? b1 : b2;
#pragma unroll
        for (int j = 0; j < 4; ++j) {
            int col = col0 + j * 16 + l15;
            float bb = bp[col];
#pragma unroll
            for (int r = 0; r < 4; ++r) {
                int grow = row0 + w * 16 + quad * 4 + r;
                if (grow < n) {
                    float v = acc[j][r] + bb;
                    if (mat == 0) out0[(size_t)grow * 128 + col] = bf16of(v);
                    else if (mat == 1) out1[(size_t)grow * 128 + col] = v;
                    else out2[(size_t)grow * 128 + col] = v;
                }
            }
        }
        __syncthreads();
    }
}

// ---------------- scan final (block-sum scan inlined as a wave scan) ----------------
__global__ __launch_bounds__(256) void scan_final_kernel(
    const u32* __restrict__ counts, const u32* __restrict__ bsums, int* __restrict__ rowptr)
{
    __shared__ u32 ls[256];
    __shared__ u32 prefsh;
    int t = threadIdx.x;
    if (t < 64) {
        u32 v = (t < 49) ? bsums[t] : 0u;
#pragma unroll
        for (int off = 1; off < 64; off <<= 1) {
            u32 tv = __shfl_up(v, off, 64);
            if (t >= off) v += tv;
        }
        u32 ex = __shfl_up(v, 1, 64);
        if (t == 0) ex = 0u;
        if (t == (int)blockIdx.x) prefsh = ex;
    }
    __syncthreads();
    u32 bpref = prefsh;
    int base = blockIdx.x * 1024 + t * 4;
    u32 c[4];
    u32 s = 0;
#pragma unroll
    for (int j = 0; j < 4; ++j) { int idx = base + j; c[j] = (idx < NN) ? counts[idx] : 0u; s += c[j]; }
    ls[t] = s;
    __syncthreads();
    for (int off = 1; off < 256; off <<= 1) {
        u32 add = (t >= off) ? ls[t - off] : 0u;
        __syncthreads();
        ls[t] += add;
        __syncthreads();
    }
    u32 run = ls[t] - s + bpref;
#pragma unroll
    for (int j = 0; j < 4; ++j) { int idx = base + j; if (idx < NN) { rowptr[idx] = (int)run; } run += c[j]; }
    if (blockIdx.x == 0 && t == 0) rowptr[NN] = NE;
}

// ---------------- scatter: CSR-order srcs + CSR-order packed edge attrs ----------------
__global__ __launch_bounds__(256) void scatter_pack_kernel(
    const int* __restrict__ ei, const float* __restrict__ ea, const int* __restrict__ rowptr,
    u32* __restrict__ cursors, int* __restrict__ srcs, u32* __restrict__ eahs)
{
    int e = blockIdx.x * 256 + threadIdx.x;
    if (e < NE) {
        int sn = ei[e];
        int d = ei[NE + e];
        u32 pos = atomicAdd(&cursors[d], 1u);
        int slot = rowptr[d] + (int)pos;
        srcs[slot] = sn;
        const float4* s4 = (const float4*)(ea + (size_t)e * 16);
        float4 f0 = s4[0], f1 = s4[1], f2 = s4[2], f3 = s4[3];
        uint4 o0 = {bfpack2(f0.x, f0.y), bfpack2(f0.z, f0.w), bfpack2(f1.x, f1.y), bfpack2(f1.z, f1.w)};
        uint4 o1 = {bfpack2(f2.x, f2.y), bfpack2(f2.z, f2.w), bfpack2(f3.x, f3.y), bfpack2(f3.z, f3.w)};
        *(uint4*)(eahs + (size_t)slot * 8) = o0;
        *(uint4*)(eahs + (size_t)slot * 8 + 4) = o1;
    }
}

// ---------------- fused GATv2 layer 1 (H=2, C=64) ----------------
// 1 node/wave, oversubscribed 12500-block grid (scheduler backfill beats
// wave-level chunking: R14's exactly-resident persistent grid REGRESSED
// 82->89us with occupancy 51->35). 2-deep pipeline pinned by sched_barrier(0).
__global__ __launch_bounds__(256) void gat1_fused_kernel(
    const u32* __restrict__ xlp, const float* __restrict__ xr,
    const u32* __restrict__ eahs, const int* __restrict__ srcs,
    const int* __restrict__ rowptr, const float* __restrict__ We,
    const float* __restrict__ att, const float* __restrict__ bias,
    float* __restrict__ out)
{
    int lane = threadIdx.x & 63;
    int d = (blockIdx.x * 256 + threadIdx.x) >> 6;
    if (d >= NN) return;
    int du = __builtin_amdgcn_readfirstlane(d);
    int beg = rowptr[du], end = rowptr[du + 1];
    int c0 = lane * 2;
    v2f w[16];
#pragma unroll
    for (int k = 0; k < 16; ++k) {
        float2 t2 = *(const float2*)(We + k * 128 + c0);
        w[k] = (v2f){t2.x, t2.y};
    }
    float at0 = att[c0], at1 = att[c0 + 1];
    float2 bt = *(const float2*)(bias + c0);
    float2 xq = *(const float2*)(xr + (size_t)du * 128 + c0);
    v2f xrv = {xq.x, xq.y};

    float s = 0.f;
    v2f acc = {0.f, 0.f};

    int cnt = (end - beg) >> 2;
    int sA[4]; uint4 eA0[4], eA1[4]; u32 xA[4];
    int sB[4]; uint4 eB0[4], eB1[4]; u32 xB[4];

#define G1_LOAD(SN, E0, E1, X, base_) do {                                     \
    _Pragma("unroll")                                                          \
    for (int j = 0; j < 4; ++j) SN[j] = srcs[(base_) + j];                     \
    _Pragma("unroll")                                                          \
    for (int j = 0; j < 4; ++j) {                                              \
        const uint4* e4_ = (const uint4*)(eahs + (size_t)((base_) + j) * 8);   \
        E0[j] = e4_[0]; E1[j] = e4_[1];                                        \
    }                                                                          \
    _Pragma("unroll")                                                          \
    for (int j = 0; j < 4; ++j) X[j] = xlp[(size_t)SN[j] * 64 + lane];         \
    __builtin_amdgcn_sched_barrier(0);                                         \
} while (0)

#define G1_PROC(E0, E1, X) do {                                                \
    float q[4]; v2f xv[4];                                                     \
    _Pragma("unroll")                                                          \
    for (int j = 0; j < 4; ++j) {                                              \
        u32 ew[8] = {E0[j].x, E0[j].y, E0[j].z, E0[j].w,                       \
                     E1[j].x, E1[j].y, E1[j].z, E1[j].w};                      \
        v2f e = {0.f, 0.f};                                                    \
        _Pragma("unroll")                                                      \
        for (int kk = 0; kk < 8; ++kk) {                                       \
            u32 pk = ew[kk];                                                   \
            float s1 = uaf(pk << 16), s2 = uaf(pk & 0xffff0000u);              \
            e = fma2(w[2 * kk],     (v2f){s1, s1}, e);                         \
            e = fma2(w[2 * kk + 1], (v2f){s2, s2}, e);                         \
        }                                                                      \
        u32 pxv = X[j];                                                        \
        xv[j] = (v2f){uaf(pxv << 16), uaf(pxv & 0xffff0000u)};                 \
        v2f mm = xv[j] + xrv + e;                                              \
        v2f lk = max2(mm, mm * 0.2f);                                          \
        q[j] = fmaf(lk.x, at0, lk.y * at1);                                    \
    }                                                                          \
    RED4_STAGES(q);                                                            \
    _Pragma("unroll")                                                          \
    for (int j = 0; j < 4; ++j) q[j] = swz_xor16_add(q[j]);                    \
    float w0 = __expf(q[0]), w1 = __expf(q[1]);                                \
    float w2 = __expf(q[2]), w3 = __expf(q[3]);                                \
    s += (w0 + w1) + (w2 + w3);                                                \
    acc = fma2(xv[0], (v2f){w0, w0}, acc);                                     \
    acc = fma2(xv[1], (v2f){w1, w1}, acc);                                     \
    acc = fma2(xv[2], (v2f){w2, w2}, acc);                                     \
    acc = fma2(xv[3], (v2f){w3, w3}, acc);                                     \
} while (0)

    if (cnt > 0) {
        G1_LOAD(sA, eA0, eA1, xA, beg);
        int g = 0;
        for (; g + 2 <= cnt; g += 2) {
            G1_LOAD(sB, eB0, eB1, xB, beg + (g + 1) * 4);
            G1_PROC(eA0, eA1, xA);
            if (g + 2 < cnt) G1_LOAD(sA, eA0, eA1, xA, beg + (g + 2) * 4);
            G1_PROC(eB0, eB1, xB);
        }
        if (g < cnt) G1_PROC(eA0, eA1, xA);
    }
#undef G1_LOAD
#undef G1_PROC
    for (int i = beg + cnt * 4; i < end; ++i) {
        const uint4* e4 = (const uint4*)(eahs + (size_t)i * 8);
        uint4 ql = e4[0], qh = e4[1];
        u32 er[8] = {ql.x, ql.y, ql.z, ql.w, qh.x, qh.y, qh.z, qh.w};
        int sn = srcs[i];
        u32 px = xlp[(size_t)sn * 64 + lane];
        v2f e = {0.f, 0.f};
#pragma unroll
        for (int kk = 0; kk < 8; ++kk) {
            u32 pk = er[kk];
            float s1 = uaf(pk << 16), s2 = uaf(pk & 0xffff0000u);
            e = fma2(w[2 * kk],     (v2f){s1, s1}, e);
            e = fma2(w[2 * kk + 1], (v2f){s2, s2}, e);
        }
        v2f xv = {uaf(px << 16), uaf(px & 0xffff0000u)};
        v2f mm = xv + xrv + e;
        v2f lk = max2(mm, mm * 0.2f);
        float p = fmaf(lk.x, at0, lk.y * at1);
        p = dpp_add<0xB1>(p);
        p = dpp_add<0x4E>(p);
        p = dpp_add<0x141>(p);
        p = dpp_add<0x140>(p);
        p = swz_xor16_add(p);
        float ww = __expf(p);
        s += ww;
        acc = fma2(xv, (v2f){ww, ww}, acc);
    }
    float inv = 1.f / (s + 1e-16f);
    float2 o;
    o.x = fmaf(acc.x, inv, bt.x);
    o.y = fmaf(acc.y, inv, bt.y);
    *(float2*)(out + (size_t)d * 128 + c0) = o;
}

// ---------------- fused GATv2 layer 2 (H=1, C=64) ----------------
__global__ __launch_bounds__(256) void gat2_fused_kernel(
    const u16* __restrict__ xlp, const float* __restrict__ xr,
    const u32* __restrict__ eahs, const int* __restrict__ srcs,
    const int* __restrict__ rowptr, const float* __restrict__ We,
    const float* __restrict__ att, const float* __restrict__ bias,
    float* __restrict__ out)
{
    int lane = threadIdx.x & 63;
    int d = (blockIdx.x * 256 + threadIdx.x) >> 6;
    if (d >= NN) return;
    int du = __builtin_amdgcn_readfirstlane(d);
    int beg = rowptr[du], end = rowptr[du + 1];
    float w[16];
#pragma unroll
    for (int k = 0; k < 16; ++k) w[k] = We[k * 64 + lane];
    float at0 = att[lane];
    float bb = bias[lane];
    float xrv = xr[(size_t)du * 64 + lane];

    float s = 0.f, acc = 0.f;

    int cnt = (end - beg) >> 2;
    int sA[4]; uint4 eA0[4], eA1[4]; float xA[4];
    int sB[4]; uint4 eB0[4], eB1[4]; float xB[4];

#define G2_LOAD(SN, E0, E1, X, base_) do {                                     \
    _Pragma("unroll")                                                          \
    for (int j = 0; j < 4; ++j) SN[j] = srcs[(base_) + j];                     \
    _Pragma("unroll")                                                          \
    for (int j = 0; j < 4; ++j) {                                              \
        const uint4* e4_ = (const uint4*)(eahs + (size_t)((base_) + j) * 8);   \
        E0[j] = e4_[0]; E1[j] = e4_[1];                                        \
    }                                                                          \
    _Pragma("unroll")                                                          \
    for (int j = 0; j < 4; ++j)                                                \
        X[j] = uaf((u32)xlp[(size_t)SN[j] * 64 + lane] << 16);                 \
    __builtin_amdgcn_sched_barrier(0);                                         \
} while (0)

#define G2_PROC(E0, E1, X) do {                                                \
    float q[4];                                                                \
    _Pragma("unroll")                                                          \
    for (int j = 0; j < 4; ++j) {                                              \
        u32 ew[8] = {E0[j].x, E0[j].y, E0[j].z, E0[j].w,                       \
                     E1[j].x, E1[j].y, E1[j].z, E1[j].w};                      \
        float e = 0.f;                                                         \
        _Pragma("unroll")                                                      \
        for (int kk = 0; kk < 8; ++kk) {                                       \
            u32 pk = ew[kk];                                                   \
            float s1 = uaf(pk << 16), s2 = uaf(pk & 0xffff0000u);              \
            e = fmaf(s1, w[2 * kk], e);                                        \
            e = fmaf(s2, w[2 * kk + 1], e);                                    \
        }                                                                      \
        float mm = X[j] + xrv + e;                                             \
        mm = fmaxf(mm, 0.2f * mm);                                             \
        q[j] = mm * at0;                                                       \
    }                                                                          \
    RED4_STAGES(q);                                                            \
    _Pragma("unroll")                                                          \
    for (int j = 0; j < 4; ++j) { q[j] = swz_xor16_add(q[j]); q[j] = total64(q[j]); } \
    float w0 = __expf(q[0]), w1 = __expf(q[1]);                                \
    float w2 = __expf(q[2]), w3 = __expf(q[3]);                                \
    s += (w0 + w1) + (w2 + w3);                                                \
    acc += fmaf(w0, X[0], fmaf(w1, X[1], fmaf(w2, X[2], w3 * X[3])));          \
} while (0)

    if (cnt > 0) {
        G2_LOAD(sA, eA0, eA1, xA, beg);
        int g = 0;
        for (; g + 2 <= cnt; g += 2) {
            G2_LOAD(sB, eB0, eB1, xB, beg + (g + 1) * 4);
            G2_PROC(eA0, eA1, xA);
            if (g + 2 < cnt) G2_LOAD(sA, eA0, eA1, xA, beg + (g + 2) * 4);
            G2_PROC(eB0, eB1, xB);
        }
        if (g < cnt) G2_PROC(eA0, eA1, xA);
    }
#undef G2_LOAD
#undef G2_PROC
    for (int i = beg + cnt * 4; i < end; ++i) {
        const uint4* e4 = (const uint4*)(eahs + (size_t)i * 8);
        uint4 ql = e4[0], qh = e4[1];
        u32 er[8] = {ql.x, ql.y, ql.z, ql.w, qh.x, qh.y, qh.z, qh.w};
        int sn = srcs[i];
        float xv = uaf((u32)xlp[(size_t)sn * 64 + lane] << 16);
        float e = 0.f;
#pragma unroll
        for (int kk = 0; kk < 8; ++kk) {
            u32 pk = er[kk];
            float s1 = uaf(pk << 16), s2 = uaf(pk & 0xffff0000u);
            e = fmaf(s1, w[2 * kk], e);
            e = fmaf(s2, w[2 * kk + 1], e);
        }
        float mm = xv + xrv + e;
        mm = fmaxf(mm, 0.2f * mm);
        float p = mm * at0;
        p = dpp_add<0xB1>(p);
        p = dpp_add<0x4E>(p);
        p = dpp_add<0x141>(p);
        p = dpp_add<0x140>(p);
        p = swz_xor16_add(p);
        p = total64(p);
        float ww = __expf(p);
        s += ww;
        acc = fmaf(ww, xv, acc);
    }
    out[(size_t)d * 64 + lane] = acc / (s + 1e-16f) + bb;
}

// ---------------- fused MFMA GEMM, layer 2 (BN1+skip+ELU+pack in staging) ----------------
__global__ __launch_bounds__(256) void gemm2_fused_kernel(
    const float* __restrict__ H, const float* __restrict__ XPin,
    const float* __restrict__ stats, const float* __restrict__ bg, const float* __restrict__ bbv,
    const u32* __restrict__ Wt,
    u16* __restrict__ out0, float* __restrict__ out1, float* __restrict__ out2,
    const float* __restrict__ b0, const float* __restrict__ b1, const float* __restrict__ b2,
    int n)
{
    __shared__ __align__(16) u32 Xs[64 * 68];
    __shared__ __align__(16) u32 Ws[64 * 68];
    int t = threadIdx.x;
    int row0 = blockIdx.x * 64;
    int c = t & 63;
    int ch0 = 2 * c, ch1 = ch0 + 1;
    float mu0 = stats[ch0] * (1.f / NN), mu1 = stats[ch1] * (1.f / NN);
    float var0 = stats[128 + ch0] * (1.f / NN) - mu0 * mu0;
    float var1 = stats[128 + ch1] * (1.f / NN) - mu1 * mu1;
    float s0 = rsqrtf(var0 + 1e-5f) * bg[ch0];
    float s1 = rsqrtf(var1 + 1e-5f) * bg[ch1];
    float t0 = bbv[ch0] - mu0 * s0;
    float t1 = bbv[ch1] - mu1 * s1;
#pragma unroll
    for (int i = 0; i < 16; ++i) {
        int flat = t + 256 * i;
        int r = flat >> 6;
        int gr = row0 + r;
        u32 v = 0u;
        if (gr < n) {
            float2 hv = *(const float2*)(H + (size_t)gr * 128 + ch0);
            float2 xv = *(const float2*)(XPin + (size_t)gr * 128 + ch0);
            float v0 = fmaf(hv.x, s0, t0) + xv.x;
            float v1 = fmaf(hv.y, s1, t1) + xv.y;
            v0 = (v0 > 0.f) ? v0 : expm1f(v0);
            v1 = (v1 > 0.f) ? v1 : expm1f(v1);
            v = bfpack2(v0, v1);
        }
        Xs[r * 68 + c] = v;
    }
    int w = t >> 6, lane = t & 63;
    int l15 = lane & 15, quad = lane >> 4;
    for (int nb = 0; nb < 3; ++nb) {
#pragma unroll
        for (int i = 0; i < 16; ++i) {
            int flat = t + 256 * i;
            int cc = flat >> 6, cw = flat & 63;
            Ws[cc * 68 + cw] = Wt[(size_t)(nb * 64 + cc) * 64 + cw];
        }
        __syncthreads();
        f32x4 acc[4] = {};
#pragma unroll
        for (int kk = 0; kk < 4; ++kk) {
            bf16x8 af = *(const bf16x8*)&Xs[(w * 16 + l15) * 68 + kk * 16 + quad * 4];
#pragma unroll
            for (int j = 0; j < 4; ++j) {
                bf16x8 bf = *(const bf16x8*)&Ws[(j * 16 + l15) * 68 + kk * 16 + quad * 4];
                acc[j] = __builtin_amdgcn_mfma_f32_16x16x32_bf16(af, bf, acc[j], 0, 0, 0);
            }
        }
        const float* bp = (nb == 0) ? b0 : (nb == 1) ? b1 : b2;
#pragma unroll
        for (int j = 0; j < 4; ++j) {
            int col = j * 16 + l15;
            float bb = bp[col];
#pragma unroll
            for (int r = 0; r < 4; ++r) {
                int grow = row0 + w * 16 + quad * 4 + r;
                if (grow < n) {
                    float v = acc[j][r] + bb;
                    if (nb == 0) out0[(size_t)grow * 64 + col] = bf16of(v);
                    else if (nb == 1) out1[(size_t)grow * 64 + col] = v;
                    else out2[(size_t)grow * 64 + col] = v;
                }
            }
        }
        __syncthreads();
    }
}

// ---------------- batch-norm stats (391 blocks: full CU coverage) ----------------
template <int C>
__global__ __launch_bounds__(256) void bn_stats_kernel(const float* __restrict__ h, float* __restrict__ stats) {
    const int SUB = 256 / C;
    int t = threadIdx.x;
    int c = t & (C - 1);
    int rs = t / C;
    int r0 = blockIdx.x * 128;
    int r1 = min(NN, r0 + 128);
    float s = 0.f, s2 = 0.f;
    for (int r = r0 + rs; r < r1; r += SUB) {
        float v = h[(size_t)r * C + c];
        s += v; s2 = fmaf(v, v, s2);
    }
    __shared__ float ls[256], ls2[256];
    ls[t] = s; ls2[t] = s2;
    __syncthreads();
    if (rs == 0) {
        for (int j = 1; j < SUB; ++j) { s += ls[j * C + c]; s2 += ls2[j * C + c]; }
        atomicAdd(&stats[c], s);
        atomicAdd(&stats[C + c], s2);
    }
}

// ---------------- pool accumulate: BN2+skip+ELU fused, per-graph atomic sum/max ----------------
__global__ __launch_bounds__(256) void pool_acc_kernel(
    const float* __restrict__ D, const float* __restrict__ xp2,
    const float* __restrict__ stats, const float* __restrict__ bg, const float* __restrict__ bbv,
    const int* __restrict__ batch,
    float* __restrict__ psum, u32* __restrict__ pmax)
{
    int t = threadIdx.x;
    int lane = t & 63, rs = t >> 6;
    float mu = stats[lane] * (1.f / NN);
    float var = stats[64 + lane] * (1.f / NN) - mu * mu;
    float sc = rsqrtf(var + 1e-5f) * bg[lane];
    float tb = bbv[lane] - mu * sc;
    int r0 = blockIdx.x * 128;
    int r1 = min(NN, r0 + 128);
    int curg = -1;
    float sum = 0.f, mx = -INFINITY;
    for (int r = r0 + rs; r < r1; r += 4) {
        int g = batch[r];               // wave-uniform (lane indexes channel only)
        if (g != curg) {
            if (curg >= 0) {
                atomicAdd(&psum[curg * 64 + lane], sum);
                atomicMax(&pmax[curg * 64 + lane], fenc(mx));
            }
            curg = g; sum = 0.f; mx = -INFINITY;
        }
        float v = fmaf(D[(size_t)r * 64 + lane], sc, tb) + xp2[(size_t)r * 64 + lane];
        v = (v > 0.f) ? v : expm1f(v);
        sum += v; mx = fmaxf(mx, v);
    }
    if (curg >= 0) {
        atomicAdd(&psum[curg * 64 + lane], sum);
        atomicMax(&pmax[curg * 64 + lane], fenc(mx));
    }
}

// ---------------- pool finalize + classifier (tiny) ----------------
__global__ __launch_bounds__(64) void pool_fin_kernel(
    const float* __restrict__ psum, const u32* __restrict__ pmax,
    const int* __restrict__ batch,
    const float* __restrict__ cw, const float* __restrict__ cb,
    float* __restrict__ outp)
{
    int g = blockIdx.x;
    int lane = threadIdx.x;
    int lo = 0, hi = NN;
    while (lo < hi) { int mid = (lo + hi) >> 1; if (batch[mid] < g) lo = mid + 1; else hi = mid; }
    int s0 = lo;
    hi = NN;
    while (lo < hi) { int mid = (lo + hi) >> 1; if (batch[mid] < g + 1) lo = mid + 1; else hi = mid; }
    int e0 = lo;
    float cnt = (float)(e0 - s0);
    float mean = psum[g * 64 + lane] / fmaxf(cnt, 1.f);
    float mx = fdec(pmax[g * 64 + lane]);
#pragma unroll
    for (int c = 0; c < 2; ++c) {
        float v = fmaf(mean, cw[lane * 2 + c], mx * cw[(64 + lane) * 2 + c]);
        v = dpp_add<0xB1>(v);
        v = dpp_add<0x4E>(v);
        v = dpp_add<0x141>(v);
        v = dpp_add<0x140>(v);
        v = swz_xor16_add(v);
        v = total64(v);
        if (lane == 0) outp[g * 2 + c] = v + cb[c];
    }
}

extern "C" void kernel_launch(void* const* d_in, const int* in_sizes, int n_in,
                              void* d_out, int out_size, void* d_ws, size_t ws_size,
                              hipStream_t stream)
{
    const float* x       = (const float*)d_in[0];
    const int*   ei      = (const int*)d_in[1];
    const float* ea      = (const float*)d_in[2];
    const int*   batch   = (const int*)d_in[3];
    const float* skip1_w = (const float*)d_in[4];
    const float* skip1_b = (const float*)d_in[5];
    const float* c1_wl   = (const float*)d_in[6];
    const float* c1_bl   = (const float*)d_in[7];
    const float* c1_wr   = (const float*)d_in[8];
    const float* c1_br   = (const float*)d_in[9];
    const float* c1_we   = (const float*)d_in[10];
    const float* c1_att  = (const float*)d_in[11];
    const float* c1_bias = (const float*)d_in[12];
    const float* bn1_g   = (const float*)d_in[13];
    const float* bn1_b   = (const float*)d_in[14];
    const float* skip2_w = (const float*)d_in[15];
    const float* skip2_b = (const float*)d_in[16];
    const float* c2_wl   = (const float*)d_in[17];
    const float* c2_bl   = (const float*)d_in[18];
    const float* c2_wr   = (const float*)d_in[19];
    const float* c2_br   = (const float*)d_in[20];
    const float* c2_we   = (const float*)d_in[21];
    const float* c2_att  = (const float*)d_in[22];
    const float* c2_bias = (const float*)d_in[23];
    const float* bn2_g   = (const float*)d_in[24];
    const float* bn2_b   = (const float*)d_in[25];
    const float* cls_w   = (const float*)d_in[26];
    const float* cls_b   = (const float*)d_in[27];
    float* outp = (float*)d_out;

    float* ws = (float*)d_ws;
    size_t o = 0;
    float* A   = ws + o; o += 6400000;   // XL1P bf16 [n][128]; layer2: XL2P bf16 (lower) + xr2 fp32 (upper)
    float* B   = ws + o; o += 6400000;   // xr1 fp32 [n][128]
    float* Cb  = ws + o; o += 6400000;   // xp1 fp32 [n][128]
    float* D   = ws + o; o += 6400000;   // h1 pre-BN [n][128] ; later h2 pre-BN [n][64]
    int*   SRCS  = (int*)(ws + o); o += 800000;    // CSR-ordered src nodes
    u32*   EAHS  = (u32*)(ws + o); o += 6400000;   // CSR-ordered ea packed bf16 [E][8]
    u32*   XPx   = (u32*)(ws + o); o += 3200000;   // xp2 fp32 [n][64]
    u32*   WT1   = (u32*)(ws + o); o += 24576;     // [384][64]
    u32*   WT2   = (u32*)(ws + o); o += 12288;     // [192][64]
    // ---- contiguous zeroed region: COUNTS..PMAX (106784 u32) ----
    u32*   COUNTS  = (u32*)(ws + o); o += 50000;
    u32*   CURSORS = (u32*)(ws + o); o += 50000;
    float* STATS1  = ws + o; o += 256;
    float* STATS2  = ws + o; o += 128;
    float* PSUM    = ws + o; o += 3200;            // [G][64] pooled sum
    u32*   PMAX    = (u32*)(ws + o); o += 3200;    // [G][64] pooled max (monotonic enc)
    // ---- end zeroed region ----
    int*   ROWPTR  = (int*)(ws + o); o += 50016;
    u32*   BSUMS   = (u32*)(ws + o); o += 64;

    u16*   XL1P = (u16*)A;               // [n][128] bf16
    u16*   XL2P = (u16*)A;               // [n][64] bf16 (layer 2)
    float* xr2  = A + 3200000;
    float* xp2  = (float*)XPx;           // [n][64] fp32

    // zero COUNTS + CURSORS + STATS1 + STATS2 + PSUM + PMAX (contiguous, 106784 u32)
    zero_u32_kernel<<<(106784 + 255) / 256, 256, 0, stream>>>(COUNTS, 106784);
    // count_edges + wpack(WT1) + wpack(WT2) in one launch
    mega_prep_kernel<<<3269, 256, 0, stream>>>(ei, COUNTS,
        c1_wl, c1_wr, skip1_w, WT1, c2_wl, c2_wr, skip2_w, WT2);
    // scan part1 (49 blocks) runs concurrently with GEMM1 (782 blocks)
    scan1_gemm1_kernel<<<831, 256, 0, stream>>>(COUNTS, BSUMS, x, WT1,
        XL1P, B, Cb, c1_bl, c1_br, skip1_b, NN);
    scan_final_kernel<<<49, 256, 0, stream>>>(COUNTS, BSUMS, ROWPTR);
    scatter_pack_kernel<<<3125, 256, 0, stream>>>(ei, ea, ROWPTR, CURSORS, SRCS, EAHS);

    // ---- layer 1 ----
    gat1_fused_kernel<<<NN / 4, 256, 0, stream>>>((const u32*)XL1P, B, EAHS, SRCS, ROWPTR,
        c1_we, c1_att, c1_bias, D);
    bn_stats_kernel<128><<<391, 256, 0, stream>>>(D, STATS1);

    // ---- layer 2 (BN1-apply + skip + ELU fused into the GEMM staging) ----
    gemm2_fused_kernel<<<782, 256, 0, stream>>>(D, Cb, STATS1, bn1_g, bn1_b, WT2,
        XL2P, xr2, xp2, c2_bl, c2_br, skip2_b, NN);
    gat2_fused_kernel<<<NN / 4, 256, 0, stream>>>(XL2P, xr2, EAHS, SRCS, ROWPTR,
        c2_we, c2_att, c2_bias, D);
    bn_stats_kernel<64><<<391, 256, 0, stream>>>(D, STATS2);

    // ---- pool: wide atomic accumulate (BN2+skip+ELU fused) + tiny finalize/classify ----
    pool_acc_kernel<<<(NN + 127) / 128, 256, 0, stream>>>(D, xp2, STATS2, bn2_g, bn2_b,
        batch, PSUM, PMAX);
    pool_fin_kernel<<<GG, 64, 0, stream>>>(PSUM, PMAX, batch, cls_w, cls_b, outp);
}